// Round 1
// baseline (1323.689 us; speedup 1.0000x reference)
//
#include <hip/hip_runtime.h>
#include <cstdint>

#define B_  32
#define S_  512
#define H_  768
#define V_  30522
#define NT_ 24          // N_UPDATE * MAX_LEN sequential steps
#define H3  2304
#define NC4   (V_*H_/4)           // 5860224 float4 casts for E2
#define NWALL (NT_*B_*H_)         // 589824
#define NINIT (B_*H_)             // 24576
#define GRU_NBLK 192

typedef unsigned short ushort_t;
typedef __attribute__((ext_vector_type(8))) short bf16x8;
typedef __attribute__((ext_vector_type(4))) float f32x4;

__device__ __forceinline__ ushort_t f2bf(float f){
  union { float f; unsigned u; } v; v.f = f;
  unsigned r = v.u + 0x7fffu + ((v.u >> 16) & 1u);
  return (ushort_t)(r >> 16);
}

// ---------------- fused prep: E2 cast + W_all build + h0 init + zeroing ----------------
__global__ void k_prep(const float* __restrict__ embed, const float* __restrict__ dec,
                       const int* __restrict__ teacher, const float* __restrict__ hidden,
                       ushort_t* __restrict__ E2, float* __restrict__ wall,
                       float* __restrict__ Hq, float* __restrict__ Hb,
                       float* __restrict__ pgacc, unsigned* __restrict__ bar){
  int idx = blockIdx.x * 256 + threadIdx.x;
  if (idx < NC4){                                  // E2 = bf16(embed)
    float4 v = ((const float4*)embed)[idx];
    uint2 o;
    o.x = (unsigned)f2bf(v.x) | ((unsigned)f2bf(v.y) << 16);
    o.y = (unsigned)f2bf(v.z) | ((unsigned)f2bf(v.w) << 16);
    ((uint2*)E2)[idx] = o;
    return;
  }
  idx -= NC4;
  if (idx < NWALL){                                // W_all[t][b][k]
    int k  = idx % H_;
    int rb = idx / H_;
    int t = rb >> 5, b = rb & 31;
    int jj = t >> 3, kk = t & 7;
    float v;
    if (kk == 0) v = dec[(b*3 + jj)*H_ + k];
    else { int tok = teacher[(b*3 + jj)*8 + kk - 1]; v = embed[(size_t)tok*H_ + k]; }
    wall[idx] = v;
    return;
  }
  idx -= NWALL;
  if (idx < NINIT){                                // h0 -> Hb, Hq layouts
    int b = idx / H_, k = idx % H_;
    float v = hidden[idx];
    Hb[idx] = v;
    Hq[((k >> 2)*B_ + b)*4 + (k & 3)] = v;
    return;
  }
  idx -= NINIT;
  if (idx < 768){                                  // zero p_gen accumulator + barrier
    pgacc[idx] = 0.f;
    if (idx == 0) *bar = 0u;
  }
}

// ---------------- fp32 GEMM (NT) + bias:  gi = wall * wih^T + bih ----------------
// M=768, N=2304, K=768
__global__ __launch_bounds__(256) void k_gi_gemm(const float* __restrict__ A, const float* __restrict__ Bm,
                                                 const float* __restrict__ bias, float* __restrict__ C){
  __shared__ float As[16][68];
  __shared__ float Bs[16][68];
  const int tid = threadIdx.x;
  const int tx = tid & 15, ty = tid >> 4;
  const int m0 = blockIdx.x * 64, n0 = blockIdx.y * 64;
  const int r = tid >> 2, kq = tid & 3;
  float acc[4][4] = {};
  for (int k0 = 0; k0 < 768; k0 += 16){
    float4 av = *(const float4*)&A [(size_t)(m0 + r)*768 + k0 + kq*4];
    float4 bv = *(const float4*)&Bm[(size_t)(n0 + r)*768 + k0 + kq*4];
    __syncthreads();
    As[kq*4+0][r] = av.x; As[kq*4+1][r] = av.y; As[kq*4+2][r] = av.z; As[kq*4+3][r] = av.w;
    Bs[kq*4+0][r] = bv.x; Bs[kq*4+1][r] = bv.y; Bs[kq*4+2][r] = bv.z; Bs[kq*4+3][r] = bv.w;
    __syncthreads();
#pragma unroll
    for (int kk = 0; kk < 16; ++kk){
      float4 a4 = *(const float4*)&As[kk][ty*4];
      float4 b4 = *(const float4*)&Bs[kk][tx*4];
      float aa[4] = {a4.x, a4.y, a4.z, a4.w};
      float bb[4] = {b4.x, b4.y, b4.z, b4.w};
#pragma unroll
      for (int i = 0; i < 4; ++i)
#pragma unroll
        for (int j = 0; j < 4; ++j)
          acc[i][j] = fmaf(aa[i], bb[j], acc[i][j]);
    }
  }
#pragma unroll
  for (int i = 0; i < 4; ++i){
    int m = m0 + ty*4 + i;
#pragma unroll
    for (int j = 0; j < 4; ++j){
      int n = n0 + tx*4 + j;
      C[(size_t)m*H3 + n] = acc[i][j] + bias[n];
    }
  }
}

// ---------------- persistent GRU: all 24 steps, one launch ----------------
// 192 blocks x 256 threads (4 waves, one output column j per wave).
// Cross-block sync: monotonic atomic arrival counter + agent-scope fences
// (release: wb L2 so other XCDs see h; acquire: inv L1/L2 before reading h).
// 192 4-wave blocks over 256 CUs => all co-resident, spin barrier is safe.
// Also emits the bf16 A2 row (vocab-GEMM A operand) -- same f2bf as old cast.
__global__ __launch_bounds__(256) void k_gru_all(const float* __restrict__ gi, const float* __restrict__ whh,
                                                 const float* __restrict__ bhh, float* __restrict__ Hq,
                                                 float* __restrict__ Hb, ushort_t* __restrict__ A2,
                                                 unsigned* __restrict__ bar){
  const int wid  = threadIdx.x >> 6;
  const int lane = threadIdx.x & 63;
  const int j = blockIdx.x * 4 + wid;           // 0..767
  const int khalf = lane >> 5, b = lane & 31;
  const float4* wr = (const float4*)&whh[(size_t)(       j)*768 + khalf*384];
  const float4* wz = (const float4*)&whh[(size_t)(768  + j)*768 + khalf*384];
  const float4* wn = (const float4*)&whh[(size_t)(1536 + j)*768 + khalf*384];
  const float bR = bhh[j], bZ = bhh[768 + j], bN = bhh[1536 + j];
  for (int t = 0; t < NT_; ++t){
    const float4* hqp = (const float4*)(Hq + (size_t)t*24576) + (size_t)khalf*96*32 + b;
    float aR = 0.f, aZ = 0.f, aN = 0.f;
#pragma unroll 8
    for (int i = 0; i < 96; ++i){
      float4 h4 = hqp[(size_t)i*32];
      float4 r4 = wr[i], z4 = wz[i], n4 = wn[i];
      aR += h4.x*r4.x + h4.y*r4.y + h4.z*r4.z + h4.w*r4.w;
      aZ += h4.x*z4.x + h4.y*z4.y + h4.z*z4.z + h4.w*z4.w;
      aN += h4.x*n4.x + h4.y*n4.y + h4.z*n4.z + h4.w*n4.w;
    }
    aR += __shfl_xor(aR, 32, 64);
    aZ += __shfl_xor(aZ, 32, 64);
    aN += __shfl_xor(aN, 32, 64);
    if (lane < 32){
      const float* gi_t = gi + (size_t)t*B_*H3;
      float ir = gi_t[b*H3 + j], iz = gi_t[b*H3 + 768 + j], inn = gi_t[b*H3 + 1536 + j];
      float sR = aR + bR, sZ = aZ + bZ, sN = aN + bN;
      float rg = 1.f / (1.f + __expf(-(ir + sR)));
      float zg = 1.f / (1.f + __expf(-(iz + sZ)));
      float e2 = __expf(-2.f*(inn + rg * sN));
      float ng = (1.f - e2) / (1.f + e2);
      float hp = Hb[(size_t)t*24576 + b*768 + j];
      float hn = (1.f - zg)*ng + zg*hp;
      Hb[(size_t)(t+1)*24576 + b*768 + j] = hn;
      Hq[(size_t)(t+1)*24576 + ((j >> 2)*32 + b)*4 + (j & 3)] = hn;
      A2[(size_t)(t*32 + b)*768 + j] = f2bf(hn);
    }
    if (t < NT_ - 1){
      __syncthreads();                            // drains each wave's stores to L2
      if (threadIdx.x == 0){
        __builtin_amdgcn_fence(__ATOMIC_RELEASE, "agent");
        __hip_atomic_fetch_add(bar, 1u, __ATOMIC_RELAXED, __HIP_MEMORY_SCOPE_AGENT);
        const unsigned tgt = (unsigned)(GRU_NBLK * (t + 1));
        while (__hip_atomic_load(bar, __ATOMIC_RELAXED, __HIP_MEMORY_SCOPE_AGENT) < tgt)
          __builtin_amdgcn_s_sleep(1);
        __builtin_amdgcn_fence(__ATOMIC_ACQUIRE, "agent");
      }
      __syncthreads();
    }
  }
}

// ---------------- attn_e[t][b][s] = enc[b][s][:] . h[t+1][b][:]  (fp32) ----------------
__global__ __launch_bounds__(256) void k_attn(const float* __restrict__ enc, const float* __restrict__ Hb1,
                                              float* __restrict__ ae){
  __shared__ float Es[64*36];
  __shared__ float Ht[24*36];
  const int b = blockIdx.x, s0 = blockIdx.y * 64;
  const int tid = threadIdx.x;
  const int s_l = tid & 63, tq = tid >> 6;
  const int r = tid >> 2, kq = tid & 3;
  float acc[6] = {0.f,0.f,0.f,0.f,0.f,0.f};
  for (int k0 = 0; k0 < 768; k0 += 32){
    __syncthreads();
    float4 e0 = *(const float4*)&enc[(size_t)(b*512 + s0 + r)*768 + k0 + kq*8];
    float4 e1 = *(const float4*)&enc[(size_t)(b*512 + s0 + r)*768 + k0 + kq*8 + 4];
    *(float4*)&Es[r*36 + kq*8]     = e0;
    *(float4*)&Es[r*36 + kq*8 + 4] = e1;
    if (tid < 192){
      int t = tid >> 3, k4 = tid & 7;
      *(float4*)&Ht[t*36 + k4*4] = *(const float4*)&Hb1[(size_t)t*24576 + b*768 + k0 + k4*4];
    }
    __syncthreads();
#pragma unroll
    for (int k4 = 0; k4 < 8; ++k4){
      float4 e = *(const float4*)&Es[s_l*36 + k4*4];
#pragma unroll
      for (int i = 0; i < 6; ++i){
        float4 h4 = *(const float4*)&Ht[(tq*6 + i)*36 + k4*4];
        acc[i] += e.x*h4.x + e.y*h4.y + e.z*h4.z + e.w*h4.w;
      }
    }
  }
#pragma unroll
  for (int i = 0; i < 6; ++i)
    ae[(size_t)((tq*6 + i)*32 + b)*512 + s0 + s_l] = acc[i];
}

// ---------------- masked softmax over S=512, in place ----------------
__global__ __launch_bounds__(256) void k_attnsoft(const int* __restrict__ x, float* __restrict__ ae){
  const int row = blockIdx.x;            // t*32+b
  const int b = row & 31;
  const int tid = threadIdx.x;
  __shared__ float red[256];
  float v0 = ae[(size_t)row*512 + tid];
  float v1 = ae[(size_t)row*512 + 256 + tid];
  if (x[b*512 + tid]        == 0) v0 = -1e9f;
  if (x[b*512 + 256 + tid]  == 0) v1 = -1e9f;
  float m = fmaxf(v0, v1);
  red[tid] = m; __syncthreads();
  for (int off = 128; off; off >>= 1){ if (tid < off) red[tid] = fmaxf(red[tid], red[tid+off]); __syncthreads(); }
  float M = red[0]; __syncthreads();
  float e0 = __expf(v0 - M), e1 = __expf(v1 - M);
  red[tid] = e0 + e1; __syncthreads();
  for (int off = 128; off; off >>= 1){ if (tid < off) red[tid] += red[tid+off]; __syncthreads(); }
  float inv = 1.f / red[0];
  ae[(size_t)row*512 + tid]       = e0 * inv;
  ae[(size_t)row*512 + 256 + tid] = e1 * inv;
}

// ---------------- ctx reduction folded directly into p_gen partials ----------------
// context[] was consumed ONLY by p_gen -> never materialize it. Each block
// (b, ktile) computes ctx[row][k] for its 64-k slice and reduces
// wg_ctx.ctx + wg_w.wall + wg_h.h over the slice; one atomicAdd per row.
__global__ __launch_bounds__(256) void k_ctx_pgen(const float* __restrict__ enc, const float* __restrict__ ah,
                                                  const float* __restrict__ wall, const float* __restrict__ Hb1,
                                                  const float* __restrict__ wg, float* __restrict__ pgacc){
  const int b = blockIdx.x;
  const int klane = threadIdx.x & 63;
  const int k = blockIdx.y * 64 + klane;
  const int tq = threadIdx.x >> 6;
  float acc[6] = {0.f,0.f,0.f,0.f,0.f,0.f};
  for (int s4 = 0; s4 < 512; s4 += 4){
    float e0 = enc[(size_t)(b*512 + s4 + 0)*768 + k];
    float e1 = enc[(size_t)(b*512 + s4 + 1)*768 + k];
    float e2 = enc[(size_t)(b*512 + s4 + 2)*768 + k];
    float e3 = enc[(size_t)(b*512 + s4 + 3)*768 + k];
#pragma unroll
    for (int i = 0; i < 6; ++i){
      float4 a4 = *(const float4*)&ah[(size_t)((tq*6 + i)*32 + b)*512 + s4];
      acc[i] = fmaf(a4.x, e0, acc[i]); acc[i] = fmaf(a4.y, e1, acc[i]);
      acc[i] = fmaf(a4.z, e2, acc[i]); acc[i] = fmaf(a4.w, e3, acc[i]);
    }
  }
  const float wgk = wg[k], wgh = wg[768 + k], wgc = wg[1536 + k];
#pragma unroll
  for (int i = 0; i < 6; ++i){
    const int t = tq*6 + i, row = t*32 + b;
    float p = acc[i]*wgc + wall[(size_t)row*768 + k]*wgk + Hb1[(size_t)t*24576 + b*768 + k]*wgh;
#pragma unroll
    for (int off = 32; off; off >>= 1) p += __shfl_down(p, off, 64);
    if (klane == 0) atomicAdd(&pgacc[row], p);
  }
}

// ---------------- async global->LDS 16B helper ----------------
__device__ __forceinline__ void load_lds_16B(const void* g, void* l){
  auto gp = reinterpret_cast<const __attribute__((address_space(1))) unsigned int*>(
      reinterpret_cast<uintptr_t>(g));
  auto lp = reinterpret_cast<__attribute__((address_space(3))) unsigned int*>(
      reinterpret_cast<uintptr_t>(l));
  __builtin_amdgcn_global_load_lds(gp, lp, 16, 0, 0);
}

// ---------------- vocab logits GEMM (bf16 MFMA) ----------------
__global__ __launch_bounds__(256) void k_vgemm(const ushort_t* __restrict__ A2, const ushort_t* __restrict__ E2,
                                               float* __restrict__ out){
  __shared__ ushort_t ldsA[128*64];
  __shared__ ushort_t ldsB[128*64];
  const int ntile = blockIdx.x, mtile = blockIdx.y;
  const int tid = threadIdx.x;
  const int w = tid >> 6, lane = tid & 63;
  const int lrow = lane >> 3, lpos = lane & 7;
  const int wm = w >> 1, wn = w & 1;
  const int q = lane >> 4, fr = lane & 15;
  f32x4 acc[4][4];
  f32x4 zero = {0.f, 0.f, 0.f, 0.f};
#pragma unroll
  for (int a = 0; a < 4; ++a)
#pragma unroll
    for (int c = 0; c < 4; ++c) acc[a][c] = zero;

  for (int k0 = 0; k0 < 768; k0 += 64){
    __syncthreads();
#pragma unroll
    for (int i = 0; i < 4; ++i){
      int row = w*32 + i*8 + lrow;          // 0..127
      int c   = lpos ^ (row & 7);           // XOR-swizzled source chunk
      const ushort_t* srcA = A2 + (size_t)(mtile*128 + row)*768 + k0 + c*8;
      int brow = ntile*128 + row; if (brow > V_ - 1) brow = V_ - 1;
      const ushort_t* srcB = E2 + (size_t)brow*768 + k0 + c*8;
      load_lds_16B(srcA, &ldsA[row*64 + lpos*8]);
      load_lds_16B(srcB, &ldsB[row*64 + lpos*8]);
    }
    __builtin_amdgcn_s_waitcnt(0);
    __syncthreads();
#pragma unroll
    for (int s = 0; s < 2; ++s){
      bf16x8 af[4], bfr[4];
#pragma unroll
      for (int mt = 0; mt < 4; ++mt){
        int row = wm*64 + mt*16 + fr;
        int ch = (s*4 + q) ^ (row & 7);
        af[mt] = *(const bf16x8*)&ldsA[row*64 + ch*8];
      }
#pragma unroll
      for (int nt = 0; nt < 4; ++nt){
        int row = wn*64 + nt*16 + fr;
        int ch = (s*4 + q) ^ (row & 7);
        bfr[nt] = *(const bf16x8*)&ldsB[row*64 + ch*8];
      }
#pragma unroll
      for (int mt = 0; mt < 4; ++mt)
#pragma unroll
        for (int nt = 0; nt < 4; ++nt)
          acc[mt][nt] = __builtin_amdgcn_mfma_f32_16x16x32_bf16(af[mt], bfr[nt], acc[mt][nt], 0, 0, 0);
    }
  }
#pragma unroll
  for (int mt = 0; mt < 4; ++mt){
#pragma unroll
    for (int nt = 0; nt < 4; ++nt){
      int gn = ntile*128 + wn*64 + nt*16 + fr;
      if (gn >= V_) continue;
#pragma unroll
      for (int rg = 0; rg < 4; ++rg){
        int gm = mtile*128 + wm*64 + mt*16 + q*4 + rg;   // A row = t*32+b
        int t = gm >> 5, b = gm & 31;
        out[(size_t)(b*24 + t)*V_ + gn] = acc[mt][nt][rg];
      }
    }
  }
}

// ---------------- vocab softmax * p_gen + fused scatter, in place ----------------
// p_gen from the atomically-accumulated pre-sigmoid dot; after the normalize
// pass this block owns its whole row, so it applies its own 512 scatter adds.
// The agent release fence (wbl2) publishes the dense stores before the RMWs.
__global__ __launch_bounds__(512) void k_vsoft_sc(float* __restrict__ out, const float* __restrict__ pgacc,
                                                  const float* __restrict__ wgb, const float* __restrict__ ah,
                                                  const int* __restrict__ x){
  const int row = blockIdx.x;            // b*24+t
  const int b = row / 24, t = row % 24;
  const float pg = 1.f / (1.f + __expf(-(pgacc[t*32 + b] + wgb[0])));
  const int tid = threadIdx.x;
  float* rp = out + (size_t)row * V_;
  const float4* rp4 = (const float4*)rp;
  float m = -3.0e38f, s = 0.f;
  for (int i = tid; i < 7630; i += 512){
    float4 v = rp4[i];
    float vm = fmaxf(fmaxf(v.x, v.y), fmaxf(v.z, v.w));
    float vs = __expf(v.x - vm) + __expf(v.y - vm) + __expf(v.z - vm) + __expf(v.w - vm);
    float nm = fmaxf(m, vm);
    s = s * __expf(m - nm) + vs * __expf(vm - nm);
    m = nm;
  }
  if (tid < 2){
    float v = rp[30520 + tid];
    float nm = fmaxf(m, v);
    s = s * __expf(m - nm) + __expf(v - nm);
    m = nm;
  }
#pragma unroll
  for (int off = 1; off < 64; off <<= 1){
    float m2 = __shfl_xor(m, off, 64), s2 = __shfl_xor(s, off, 64);
    float nm = fmaxf(m, m2);
    s = s*__expf(m - nm) + s2*__expf(m2 - nm);
    m = nm;
  }
  __shared__ float rm[8], rs[8];
  const int wid = tid >> 6;
  if ((tid & 63) == 0){ rm[wid] = m; rs[wid] = s; }
  __syncthreads();
  if (tid == 0){
    float M = rm[0], S = rs[0];
#pragma unroll
    for (int i = 1; i < 8; ++i){
      float m2 = rm[i], s2 = rs[i];
      float nm = fmaxf(M, m2);
      S = S*__expf(M - nm) + s2*__expf(m2 - nm);
      M = nm;
    }
    rm[0] = M; rs[0] = pg / S;
  }
  __syncthreads();
  const float M = rm[0], inv = rs[0];
  for (int i = tid; i < 7630; i += 512){
    float4 v = rp4[i];
    v.x = __expf(v.x - M) * inv;
    v.y = __expf(v.y - M) * inv;
    v.z = __expf(v.z - M) * inv;
    v.w = __expf(v.w - M) * inv;
    ((float4*)rp)[i] = v;
  }
  if (tid < 2) rp[30520 + tid] = __expf(rp[30520 + tid] - M) * inv;
  // ---- fused scatter: this block owns the row; publish dense stores first ----
  __syncthreads();                                  // all waves' stores drained to L2
  __builtin_amdgcn_fence(__ATOMIC_RELEASE, "agent");// wb L2 -> RMWs see fresh data
  {
    float val = ah[(size_t)(t*32 + b)*512 + tid] * (1.f - pg);
    int col = x[b*512 + tid];
    atomicAdd(&rp[col], val);
  }
}

extern "C" void kernel_launch(void* const* d_in, const int* in_sizes, int n_in,
                              void* d_out, int out_size, void* d_ws, size_t ws_size,
                              hipStream_t stream){
  (void)in_sizes; (void)n_in; (void)out_size; (void)ws_size;
  const int*   x      = (const int*)  d_in[0];
  const float* dec    = (const float*)d_in[1];
  const float* enc    = (const float*)d_in[2];
  const float* hidden = (const float*)d_in[3];
  const int*   teach  = (const int*)  d_in[4];
  const float* embed  = (const float*)d_in[5];
  const float* wih    = (const float*)d_in[6];
  const float* whh    = (const float*)d_in[7];
  const float* bih    = (const float*)d_in[8];
  const float* bhh    = (const float*)d_in[9];
  const float* wg     = (const float*)d_in[10];
  const float* wgb    = (const float*)d_in[11];
  float* out = (float*)d_out;

  char* p = (char*)d_ws;
  auto alloc = [&](size_t bytes){ void* r = (void*)p; p += (bytes + 255) & ~(size_t)255; return r; };
  ushort_t* E2  = (ushort_t*)alloc((size_t)V_ * H_ * 2);            // 46.9 MB
  ushort_t* A2  = (ushort_t*)alloc((size_t)768 * 768 * 2);          // 1.2 MB
  float* wall   = (float*)alloc((size_t)NT_ * B_ * H_ * 4);         // 2.4 MB
  float* Hb     = (float*)alloc((size_t)(NT_+1) * B_ * H_ * 4);     // 2.5 MB
  float* Hq     = (float*)alloc((size_t)(NT_+1) * B_ * H_ * 4);     // 2.5 MB
  float* gi     = (float*)alloc((size_t)NT_ * B_ * H3 * 4);         // 7.1 MB
  float* ae     = (float*)alloc((size_t)NT_ * B_ * S_ * 4);         // 1.6 MB
  float* pgacc  = (float*)alloc(768 * 4);
  unsigned* bar = (unsigned*)alloc(256);

  const int prep_items  = NC4 + NWALL + NINIT + 768;
  const int prep_blocks = (prep_items + 255) / 256;

  // 8 dispatches total (was 36)
  k_prep<<<prep_blocks, 256, 0, stream>>>(embed, dec, teach, hidden, E2, wall, Hq, Hb, pgacc, bar);
  k_gi_gemm<<<dim3(12, 36), 256, 0, stream>>>(wall, wih, bih, gi);
  k_gru_all<<<GRU_NBLK, 256, 0, stream>>>(gi, whh, bhh, Hq, Hb, A2, bar);
  k_attn<<<dim3(32, 8), 256, 0, stream>>>(enc, Hb + 24576, ae);
  k_attnsoft<<<768, 256, 0, stream>>>(x, ae);
  k_ctx_pgen<<<dim3(32, 12), 256, 0, stream>>>(enc, ae, wall, Hb + 24576, wg, pgacc);
  k_vgemm<<<dim3(239, 6), 256, 0, stream>>>(A2, E2, out);
  k_vsoft_sc<<<768, 512, 0, stream>>>(out, pgacc, wgb, ae, x);
}

// Round 3
// 925.815 us; speedup vs baseline: 1.4298x; 1.4298x over previous
//
#include <hip/hip_runtime.h>
#include <cstdint>

#define B_  32
#define S_  512
#define H_  768
#define V_  30522
#define NT_ 24          // N_UPDATE * MAX_LEN sequential steps
#define H3  2304
#define NC4   (V_*H_/4)           // 5860224 float4 casts for E2
#define NWALL (NT_*B_*H_)         // 589824
#define NINIT (B_*H_)             // 24576

#define GRU_NBLK 192
#define GRU_TPB  512
#define GRU_JPB  4                // j columns per block
#define GRU_RPB  12               // rows per block = 3 gates * GRU_JPB

typedef unsigned short ushort_t;
typedef __attribute__((ext_vector_type(8))) short bf16x8;
typedef __attribute__((ext_vector_type(4))) float f32x4;

__device__ __forceinline__ ushort_t f2bf(float f){
  union { float f; unsigned u; } v; v.f = f;
  unsigned r = v.u + 0x7fffu + ((v.u >> 16) & 1u);
  return (ushort_t)(r >> 16);
}

// ---------------- async global->LDS 16B helper ----------------
__device__ __forceinline__ void load_lds_16B(const void* g, void* l){
  auto gp = reinterpret_cast<const __attribute__((address_space(1))) unsigned int*>(
      reinterpret_cast<uintptr_t>(g));
  auto lp = reinterpret_cast<__attribute__((address_space(3))) unsigned int*>(
      reinterpret_cast<uintptr_t>(l));
  __builtin_amdgcn_global_load_lds(gp, lp, 16, 0, 0);
}

// ---------------- fused prep: E2 cast + W_all build + h0 init + zeroing ----------------
__global__ void k_prep(const float* __restrict__ embed, const float* __restrict__ dec,
                       const int* __restrict__ teacher, const float* __restrict__ hidden,
                       ushort_t* __restrict__ E2, float* __restrict__ wall,
                       float* __restrict__ Hq, float* __restrict__ Hb,
                       float* __restrict__ pgacc, unsigned* __restrict__ bar){
  int idx = blockIdx.x * 256 + threadIdx.x;
  if (idx < NC4){                                  // E2 = bf16(embed)
    float4 v = ((const float4*)embed)[idx];
    uint2 o;
    o.x = (unsigned)f2bf(v.x) | ((unsigned)f2bf(v.y) << 16);
    o.y = (unsigned)f2bf(v.z) | ((unsigned)f2bf(v.w) << 16);
    ((uint2*)E2)[idx] = o;
    return;
  }
  idx -= NC4;
  if (idx < NWALL){                                // W_all[t][b][k]
    int k  = idx % H_;
    int rb = idx / H_;
    int t = rb >> 5, b = rb & 31;
    int jj = t >> 3, kk = t & 7;
    float v;
    if (kk == 0) v = dec[(b*3 + jj)*H_ + k];
    else { int tok = teacher[(b*3 + jj)*8 + kk - 1]; v = embed[(size_t)tok*H_ + k]; }
    wall[idx] = v;
    return;
  }
  idx -= NWALL;
  if (idx < NINIT){                                // h0 -> Hb, Hq layouts
    int b = idx / H_, k = idx % H_;
    float v = hidden[idx];
    Hb[idx] = v;
    Hq[((k >> 2)*B_ + b)*4 + (k & 3)] = v;
    return;
  }
  idx -= NINIT;
  if (idx < 768){                                  // zero p_gen accumulator + barrier
    pgacc[idx] = 0.f;
    if (idx == 0) *bar = 0u;
  }
}

// ---------------- fp32 GEMM (NT) + bias:  gi^T = wall * wih^T + bih ----------------
// M=768, N=2304, K=768. Output layout giT[t][n][b] (b innermost) so the GRU's
// per-step reads are lane-contiguous.
__global__ __launch_bounds__(256) void k_gi_gemm(const float* __restrict__ A, const float* __restrict__ Bm,
                                                 const float* __restrict__ bias, float* __restrict__ C){
  __shared__ float As[16][68];
  __shared__ float Bs[16][68];
  const int tid = threadIdx.x;
  const int tx = tid & 15, ty = tid >> 4;
  const int m0 = blockIdx.x * 64, n0 = blockIdx.y * 64;
  const int r = tid >> 2, kq = tid & 3;
  float acc[4][4] = {};
  for (int k0 = 0; k0 < 768; k0 += 16){
    float4 av = *(const float4*)&A [(size_t)(m0 + r)*768 + k0 + kq*4];
    float4 bv = *(const float4*)&Bm[(size_t)(n0 + r)*768 + k0 + kq*4];
    __syncthreads();
    As[kq*4+0][r] = av.x; As[kq*4+1][r] = av.y; As[kq*4+2][r] = av.z; As[kq*4+3][r] = av.w;
    Bs[kq*4+0][r] = bv.x; Bs[kq*4+1][r] = bv.y; Bs[kq*4+2][r] = bv.z; Bs[kq*4+3][r] = bv.w;
    __syncthreads();
#pragma unroll
    for (int kk = 0; kk < 16; ++kk){
      float4 a4 = *(const float4*)&As[kk][ty*4];
      float4 b4 = *(const float4*)&Bs[kk][tx*4];
      float aa[4] = {a4.x, a4.y, a4.z, a4.w};
      float bb[4] = {b4.x, b4.y, b4.z, b4.w};
#pragma unroll
      for (int i = 0; i < 4; ++i)
#pragma unroll
        for (int j = 0; j < 4; ++j)
          acc[i][j] = fmaf(aa[i], bb[j], acc[i][j]);
    }
  }
#pragma unroll
  for (int i = 0; i < 4; ++i){
    int m = m0 + ty*4 + i;
    int t = m >> 5, b = m & 31;
#pragma unroll
    for (int j = 0; j < 4; ++j){
      int n = n0 + tx*4 + j;
      C[((size_t)t*H3 + n)*32 + b] = acc[i][j] + bias[n];
    }
  }
}

// ---------------- persistent GRU v3: weights in LDS, split-K, h streamed ----------------
// 192 blocks x 512 threads. Each block owns 4 j columns (12 whh rows in LDS,
// 36.9 KB -- immune to the per-step acquire-fence cache invalidation).
// Per step: 16-way split-K dots (16 kslices x 32 b threads; h streamed from
// global, coalesced), LDS tree reduce, 128 threads finalize gates and write
// Hb/Hq(transposed)/A2(bf16). Cross-block sync: monotonic arrival counter +
// agent fences. Spin is bounded so a co-residency failure cannot hang.
__global__ __launch_bounds__(GRU_TPB) void k_gru_all(const float* __restrict__ gi, const float* __restrict__ whh,
                                                     const float* __restrict__ bhh, float* __restrict__ Hq,
                                                     float* __restrict__ Hb, ushort_t* __restrict__ A2,
                                                     unsigned* __restrict__ bar){
  __shared__ float ws[GRU_RPB*768];        // 36864 B: [r][k], r = gate*4+jl
  __shared__ float red[16*392];            // 25088 B: [ks][r*32+b], stride 392
  __shared__ float bs[GRU_RPB];
  const int tid = threadIdx.x;
  const int j0 = blockIdx.x * GRU_JPB;

  // one-time: stage this block's 12 whh rows + biases into LDS (float4, coalesced)
  for (int idx4 = tid; idx4 < GRU_RPB*192; idx4 += GRU_TPB){
    int r = idx4 / 192, k4 = idx4 % 192;
    int gate = r >> 2, jl = r & 3;
    *(float4*)&ws[r*768 + k4*4] = *(const float4*)&whh[(size_t)(gate*768 + j0 + jl)*768 + k4*4];
  }
  if (tid < GRU_RPB){
    int gate = tid >> 2, jl = tid & 3;
    bs[tid] = bhh[gate*768 + j0 + jl];
  }
  __syncthreads();

  const int ks = tid >> 5, b = tid & 31;   // compute mapping: 16 kslices x 32 batch
  const int jl = tid >> 5, bb = tid & 31;  // finalize mapping (tid < 128)
  const int j  = j0 + (jl & 3);

  for (int t = 0; t < NT_; ++t){
    const float4* hsrc = (const float4*)(Hq + (size_t)t*24576);

    // prefetch finalize inputs early (hide LLC latency under the dot loop)
    float ir = 0.f, iz = 0.f, inn = 0.f, hp = 0.f;
    if (tid < 128){
      const float* gi_t = gi + (size_t)t*H3*32;
      ir  = gi_t[(size_t)(       j)*32 + bb];
      iz  = gi_t[(size_t)(768  + j)*32 + bb];
      inn = gi_t[(size_t)(1536 + j)*32 + bb];
      hp  = Hq[(size_t)t*24576 + ((j >> 2)*32 + bb)*4 + (j & 3)];
    }

    // split-K dots: this thread's 48-k slice, all 12 rows
    float acc[GRU_RPB];
#pragma unroll
    for (int r = 0; r < GRU_RPB; ++r) acc[r] = 0.f;
#pragma unroll 4
    for (int i = 0; i < 12; ++i){
      const float4 h4 = hsrc[(ks*12 + i)*32 + b];
#pragma unroll
      for (int r = 0; r < GRU_RPB; ++r){
        const float4 w4 = *(const float4*)&ws[r*768 + ks*48 + i*4];
        acc[r] += h4.x*w4.x + h4.y*w4.y + h4.z*w4.z + h4.w*w4.w;
      }
    }
#pragma unroll
    for (int r = 0; r < GRU_RPB; ++r) red[ks*392 + r*32 + b] = acc[r];
    __syncthreads();

    // finalize: 128 threads = 4 jl x 32 b
    if (tid < 128){
      float aR = 0.f, aZ = 0.f, aN = 0.f;
#pragma unroll
      for (int k8 = 0; k8 < 16; ++k8){
        aR += red[k8*392 + (0*GRU_JPB + jl)*32 + bb];
        aZ += red[k8*392 + (1*GRU_JPB + jl)*32 + bb];
        aN += red[k8*392 + (2*GRU_JPB + jl)*32 + bb];
      }
      aR += bs[jl]; aZ += bs[GRU_JPB + jl]; aN += bs[2*GRU_JPB + jl];
      float rg = 1.f / (1.f + __expf(-(ir + aR)));
      float zg = 1.f / (1.f + __expf(-(iz + aZ)));
      float e2 = __expf(-2.f*(inn + rg * aN));
      float ng = (1.f - e2) / (1.f + e2);
      float hn = (1.f - zg)*ng + zg*hp;
      Hb[(size_t)(t+1)*24576 + bb*768 + j] = hn;
      Hq[(size_t)(t+1)*24576 + ((j >> 2)*32 + bb)*4 + (j & 3)] = hn;
      A2[(size_t)(t*32 + bb)*768 + j] = f2bf(hn);
    }

    // cross-block barrier (publish h_{t+1}); bounded spin => no hard hang
    if (t < NT_ - 1){
      __syncthreads();
      if (tid == 0){
        __builtin_amdgcn_fence(__ATOMIC_RELEASE, "agent");
        __hip_atomic_fetch_add(bar, 1u, __ATOMIC_RELAXED, __HIP_MEMORY_SCOPE_AGENT);
        const unsigned tgt = (unsigned)(GRU_NBLK * (t + 1));
        unsigned spins = 0u;
        while (__hip_atomic_load(bar, __ATOMIC_RELAXED, __HIP_MEMORY_SCOPE_AGENT) < tgt &&
               ++spins < 20000000u)
          __builtin_amdgcn_s_sleep(2);
        __builtin_amdgcn_fence(__ATOMIC_ACQUIRE, "agent");
      }
      __syncthreads();
    } else {
      __syncthreads();
    }
  }
}

// ---------------- attn_e[t][b][s] = enc[b][s][:] . h[t+1][b][:]  (fp32) ----------------
__global__ __launch_bounds__(256) void k_attn(const float* __restrict__ enc, const float* __restrict__ Hb1,
                                              float* __restrict__ ae){
  __shared__ float Es[64*36];
  __shared__ float Ht[24*36];
  const int b = blockIdx.x, s0 = blockIdx.y * 64;
  const int tid = threadIdx.x;
  const int s_l = tid & 63, tq = tid >> 6;
  const int r = tid >> 2, kq = tid & 3;
  float acc[6] = {0.f,0.f,0.f,0.f,0.f,0.f};
  for (int k0 = 0; k0 < 768; k0 += 32){
    __syncthreads();
    float4 e0 = *(const float4*)&enc[(size_t)(b*512 + s0 + r)*768 + k0 + kq*8];
    float4 e1 = *(const float4*)&enc[(size_t)(b*512 + s0 + r)*768 + k0 + kq*8 + 4];
    *(float4*)&Es[r*36 + kq*8]     = e0;
    *(float4*)&Es[r*36 + kq*8 + 4] = e1;
    if (tid < 192){
      int t = tid >> 3, k4 = tid & 7;
      *(float4*)&Ht[t*36 + k4*4] = *(const float4*)&Hb1[(size_t)t*24576 + b*768 + k0 + k4*4];
    }
    __syncthreads();
#pragma unroll
    for (int k4 = 0; k4 < 8; ++k4){
      float4 e = *(const float4*)&Es[s_l*36 + k4*4];
#pragma unroll
      for (int i = 0; i < 6; ++i){
        float4 h4 = *(const float4*)&Ht[(tq*6 + i)*36 + k4*4];
        acc[i] += e.x*h4.x + e.y*h4.y + e.z*h4.z + e.w*h4.w;
      }
    }
  }
#pragma unroll
  for (int i = 0; i < 6; ++i)
    ae[(size_t)((tq*6 + i)*32 + b)*512 + s0 + s_l] = acc[i];
}

// ---------------- masked softmax over S=512, in place ----------------
__global__ __launch_bounds__(256) void k_attnsoft(const int* __restrict__ x, float* __restrict__ ae){
  const int row = blockIdx.x;            // t*32+b
  const int b = row & 31;
  const int tid = threadIdx.x;
  __shared__ float red[256];
  float v0 = ae[(size_t)row*512 + tid];
  float v1 = ae[(size_t)row*512 + 256 + tid];
  if (x[b*512 + tid]        == 0) v0 = -1e9f;
  if (x[b*512 + 256 + tid]  == 0) v1 = -1e9f;
  float m = fmaxf(v0, v1);
  red[tid] = m; __syncthreads();
  for (int off = 128; off; off >>= 1){ if (tid < off) red[tid] = fmaxf(red[tid], red[tid+off]); __syncthreads(); }
  float M = red[0]; __syncthreads();
  float e0 = __expf(v0 - M), e1 = __expf(v1 - M);
  red[tid] = e0 + e1; __syncthreads();
  for (int off = 128; off; off >>= 1){ if (tid < off) red[tid] += red[tid+off]; __syncthreads(); }
  float inv = 1.f / red[0];
  ae[(size_t)row*512 + tid]       = e0 * inv;
  ae[(size_t)row*512 + 256 + tid] = e1 * inv;
}

// ---------------- ctx reduction folded directly into p_gen partials ----------------
__global__ __launch_bounds__(256) void k_ctx_pgen(const float* __restrict__ enc, const float* __restrict__ ah,
                                                  const float* __restrict__ wall, const float* __restrict__ Hb1,
                                                  const float* __restrict__ wg, float* __restrict__ pgacc){
  const int b = blockIdx.x;
  const int klane = threadIdx.x & 63;
  const int k = blockIdx.y * 64 + klane;
  const int tq = threadIdx.x >> 6;
  float acc[6] = {0.f,0.f,0.f,0.f,0.f,0.f};
  for (int s4 = 0; s4 < 512; s4 += 4){
    float e0 = enc[(size_t)(b*512 + s4 + 0)*768 + k];
    float e1 = enc[(size_t)(b*512 + s4 + 1)*768 + k];
    float e2 = enc[(size_t)(b*512 + s4 + 2)*768 + k];
    float e3 = enc[(size_t)(b*512 + s4 + 3)*768 + k];
#pragma unroll
    for (int i = 0; i < 6; ++i){
      float4 a4 = *(const float4*)&ah[(size_t)((tq*6 + i)*32 + b)*512 + s4];
      acc[i] = fmaf(a4.x, e0, acc[i]); acc[i] = fmaf(a4.y, e1, acc[i]);
      acc[i] = fmaf(a4.z, e2, acc[i]); acc[i] = fmaf(a4.w, e3, acc[i]);
    }
  }
  const float wgk = wg[k], wgh = wg[768 + k], wgc = wg[1536 + k];
#pragma unroll
  for (int i = 0; i < 6; ++i){
    const int t = tq*6 + i, row = t*32 + b;
    float p = acc[i]*wgc + wall[(size_t)row*768 + k]*wgk + Hb1[(size_t)t*24576 + b*768 + k]*wgh;
#pragma unroll
    for (int off = 32; off; off >>= 1) p += __shfl_down(p, off, 64);
    if (klane == 0) atomicAdd(&pgacc[row], p);
  }
}

// ---------------- vocab logits GEMM (bf16 MFMA) ----------------
__global__ __launch_bounds__(256) void k_vgemm(const ushort_t* __restrict__ A2, const ushort_t* __restrict__ E2,
                                               float* __restrict__ out){
  __shared__ ushort_t ldsA[128*64];
  __shared__ ushort_t ldsB[128*64];
  const int ntile = blockIdx.x, mtile = blockIdx.y;
  const int tid = threadIdx.x;
  const int w = tid >> 6, lane = tid & 63;
  const int lrow = lane >> 3, lpos = lane & 7;
  const int wm = w >> 1, wn = w & 1;
  const int q = lane >> 4, fr = lane & 15;
  f32x4 acc[4][4];
  f32x4 zero = {0.f, 0.f, 0.f, 0.f};
#pragma unroll
  for (int a = 0; a < 4; ++a)
#pragma unroll
    for (int c = 0; c < 4; ++c) acc[a][c] = zero;

  for (int k0 = 0; k0 < 768; k0 += 64){
    __syncthreads();
#pragma unroll
    for (int i = 0; i < 4; ++i){
      int row = w*32 + i*8 + lrow;          // 0..127
      int c   = lpos ^ (row & 7);           // XOR-swizzled source chunk
      const ushort_t* srcA = A2 + (size_t)(mtile*128 + row)*768 + k0 + c*8;
      int brow = ntile*128 + row; if (brow > V_ - 1) brow = V_ - 1;
      const ushort_t* srcB = E2 + (size_t)brow*768 + k0 + c*8;
      load_lds_16B(srcA, &ldsA[row*64 + lpos*8]);
      load_lds_16B(srcB, &ldsB[row*64 + lpos*8]);
    }
    __builtin_amdgcn_s_waitcnt(0);
    __syncthreads();
#pragma unroll
    for (int s = 0; s < 2; ++s){
      bf16x8 af[4], bfr[4];
#pragma unroll
      for (int mt = 0; mt < 4; ++mt){
        int row = wm*64 + mt*16 + fr;
        int ch = (s*4 + q) ^ (row & 7);
        af[mt] = *(const bf16x8*)&ldsA[row*64 + ch*8];
      }
#pragma unroll
      for (int nt = 0; nt < 4; ++nt){
        int row = wn*64 + nt*16 + fr;
        int ch = (s*4 + q) ^ (row & 7);
        bfr[nt] = *(const bf16x8*)&ldsB[row*64 + ch*8];
      }
#pragma unroll
      for (int mt = 0; mt < 4; ++mt)
#pragma unroll
        for (int nt = 0; nt < 4; ++nt)
          acc[mt][nt] = __builtin_amdgcn_mfma_f32_16x16x32_bf16(af[mt], bfr[nt], acc[mt][nt], 0, 0, 0);
    }
  }
#pragma unroll
  for (int mt = 0; mt < 4; ++mt){
#pragma unroll
    for (int nt = 0; nt < 4; ++nt){
      int gn = ntile*128 + wn*64 + nt*16 + fr;
      if (gn >= V_) continue;
#pragma unroll
      for (int rg = 0; rg < 4; ++rg){
        int gm = mtile*128 + wm*64 + mt*16 + q*4 + rg;   // A row = t*32+b
        int t = gm >> 5, b = gm & 31;
        out[(size_t)(b*24 + t)*V_ + gn] = acc[mt][nt][rg];
      }
    }
  }
}

// ---------------- vocab softmax (online) * p_gen, in place ----------------
__global__ __launch_bounds__(512) void k_vsoft(float* __restrict__ out, const float* __restrict__ pgacc,
                                               const float* __restrict__ wgb){
  const int row = blockIdx.x;            // b*24+t
  const int b = row / 24, t = row % 24;
  const float pg = 1.f / (1.f + __expf(-(pgacc[t*32 + b] + wgb[0])));
  const int tid = threadIdx.x;
  float* rp = out + (size_t)row * V_;
  const float4* rp4 = (const float4*)rp;
  float m = -3.0e38f, s = 0.f;
  for (int i = tid; i < 7630; i += 512){
    float4 v = rp4[i];
    float vm = fmaxf(fmaxf(v.x, v.y), fmaxf(v.z, v.w));
    float vs = __expf(v.x - vm) + __expf(v.y - vm) + __expf(v.z - vm) + __expf(v.w - vm);
    float nm = fmaxf(m, vm);
    s = s * __expf(m - nm) + vs * __expf(vm - nm);
    m = nm;
  }
  if (tid < 2){
    float v = rp[30520 + tid];
    float nm = fmaxf(m, v);
    s = s * __expf(m - nm) + __expf(v - nm);
    m = nm;
  }
#pragma unroll
  for (int off = 1; off < 64; off <<= 1){
    float m2 = __shfl_xor(m, off, 64), s2 = __shfl_xor(s, off, 64);
    float nm = fmaxf(m, m2);
    s = s*__expf(m - nm) + s2*__expf(m2 - nm);
    m = nm;
  }
  __shared__ float rm[8], rs[8];
  const int wid = tid >> 6;
  if ((tid & 63) == 0){ rm[wid] = m; rs[wid] = s; }
  __syncthreads();
  if (tid == 0){
    float M = rm[0], S = rs[0];
#pragma unroll
    for (int i = 1; i < 8; ++i){
      float m2 = rm[i], s2 = rs[i];
      float nm = fmaxf(M, m2);
      S = S*__expf(M - nm) + s2*__expf(m2 - nm);
      M = nm;
    }
    rm[0] = M; rs[0] = pg / S;
  }
  __syncthreads();
  const float M = rm[0], inv = rs[0];
  for (int i = tid; i < 7630; i += 512){
    float4 v = rp4[i];
    v.x = __expf(v.x - M) * inv;
    v.y = __expf(v.y - M) * inv;
    v.z = __expf(v.z - M) * inv;
    v.w = __expf(v.w - M) * inv;
    ((float4*)rp)[i] = v;
  }
  if (tid < 2) rp[30520 + tid] = __expf(rp[30520 + tid] - M) * inv;
}

// ---------------- scatter copy-distribution (separate kernel: boundary coherence) ----------------
__global__ void k_scatter(const float* __restrict__ ah, const float* __restrict__ pgacc,
                          const float* __restrict__ wgb, const int* __restrict__ x,
                          float* __restrict__ out){
  int idx = blockIdx.x * 256 + threadIdx.x;       // over 24*32*512
  int s = idx & 511;
  int row = idx >> 9;                              // t*32+b
  int t = row >> 5, b = row & 31;
  float pg = 1.f / (1.f + __expf(-(pgacc[row] + wgb[0])));
  float val = ah[idx] * (1.f - pg);
  int col = x[b*512 + s];
  atomicAdd(&out[(size_t)(b*24 + t)*V_ + col], val);
}

extern "C" void kernel_launch(void* const* d_in, const int* in_sizes, int n_in,
                              void* d_out, int out_size, void* d_ws, size_t ws_size,
                              hipStream_t stream){
  (void)in_sizes; (void)n_in; (void)out_size; (void)ws_size;
  const int*   x      = (const int*)  d_in[0];
  const float* dec    = (const float*)d_in[1];
  const float* enc    = (const float*)d_in[2];
  const float* hidden = (const float*)d_in[3];
  const int*   teach  = (const int*)  d_in[4];
  const float* embed  = (const float*)d_in[5];
  const float* wih    = (const float*)d_in[6];
  const float* whh    = (const float*)d_in[7];
  const float* bih    = (const float*)d_in[8];
  const float* bhh    = (const float*)d_in[9];
  const float* wg     = (const float*)d_in[10];
  const float* wgb    = (const float*)d_in[11];
  float* out = (float*)d_out;

  char* p = (char*)d_ws;
  auto alloc = [&](size_t bytes){ void* r = (void*)p; p += (bytes + 255) & ~(size_t)255; return r; };
  ushort_t* E2  = (ushort_t*)alloc((size_t)V_ * H_ * 2);            // 46.9 MB
  ushort_t* A2  = (ushort_t*)alloc((size_t)768 * 768 * 2);          // 1.2 MB
  float* wall   = (float*)alloc((size_t)NT_ * B_ * H_ * 4);         // 2.4 MB
  float* Hb     = (float*)alloc((size_t)(NT_+1) * B_ * H_ * 4);     // 2.5 MB
  float* Hq     = (float*)alloc((size_t)(NT_+1) * B_ * H_ * 4);     // 2.5 MB
  float* gi     = (float*)alloc((size_t)NT_ * B_ * H3 * 4);         // 7.1 MB (giT layout [t][n][b])
  float* ae     = (float*)alloc((size_t)NT_ * B_ * S_ * 4);         // 1.6 MB
  float* pgacc  = (float*)alloc(768 * 4);
  unsigned* bar = (unsigned*)alloc(256);

  const int prep_items  = NC4 + NWALL + NINIT + 768;
  const int prep_blocks = (prep_items + 255) / 256;

  // 9 dispatches
  k_prep<<<prep_blocks, 256, 0, stream>>>(embed, dec, teach, hidden, E2, wall, Hq, Hb, pgacc, bar);
  k_gi_gemm<<<dim3(12, 36), 256, 0, stream>>>(wall, wih, bih, gi);
  k_gru_all<<<GRU_NBLK, GRU_TPB, 0, stream>>>(gi, whh, bhh, Hq, Hb, A2, bar);
  k_attn<<<dim3(32, 8), 256, 0, stream>>>(enc, Hb + 24576, ae);
  k_attnsoft<<<768, 256, 0, stream>>>(x, ae);
  k_ctx_pgen<<<dim3(32, 12), 256, 0, stream>>>(enc, ae, wall, Hb + 24576, wg, pgacc);
  k_vgemm<<<dim3(239, 6), 256, 0, stream>>>(A2, E2, out);
  k_vsoft<<<768, 512, 0, stream>>>(out, pgacc, wgb);
  k_scatter<<<(NT_*B_*S_)/256, 256, 0, stream>>>(ae, pgacc, wgb, x, out);
}

// Round 4
// 823.060 us; speedup vs baseline: 1.6083x; 1.1248x over previous
//
#include <hip/hip_runtime.h>
#include <cstdint>

#define B_  32
#define S_  512
#define H_  768
#define V_  30522
#define NT_ 24          // N_UPDATE * MAX_LEN sequential steps
#define H3  2304
#define NC4   (V_*H_/4)           // 5860224 float4 casts for E2
#define NWALL (NT_*B_*H_)         // 589824
#define NINIT (B_*H_)             // 24576

#define GRU_NBLK 192
#define GRU_TPB  512
#define GRU_JPB  4                // j columns per block
#define GRU_RPB  12               // rows per block = 3 gates * GRU_JPB

typedef unsigned short ushort_t;
typedef __attribute__((ext_vector_type(8))) short bf16x8;
typedef __attribute__((ext_vector_type(4))) float f32x4;

__device__ __forceinline__ ushort_t f2bf(float f){
  union { float f; unsigned u; } v; v.f = f;
  unsigned r = v.u + 0x7fffu + ((v.u >> 16) & 1u);
  return (ushort_t)(r >> 16);
}

// ---------------- async global->LDS 16B helper ----------------
__device__ __forceinline__ void load_lds_16B(const void* g, void* l){
  auto gp = reinterpret_cast<const __attribute__((address_space(1))) unsigned int*>(
      reinterpret_cast<uintptr_t>(g));
  auto lp = reinterpret_cast<__attribute__((address_space(3))) unsigned int*>(
      reinterpret_cast<uintptr_t>(l));
  __builtin_amdgcn_global_load_lds(gp, lp, 16, 0, 0);
}

// ---------------- fused prep: E2 cast + W_all build + h0 init + zeroing ----------------
// Hq layout (pair-major for 64-bit atomic exchange): Hq[(k>>1)*32 + b] is a
// float2 = {h[b][2k'], h[b][2k'+1]} stored as consecutive floats.
__global__ void k_prep(const float* __restrict__ embed, const float* __restrict__ dec,
                       const int* __restrict__ teacher, const float* __restrict__ hidden,
                       ushort_t* __restrict__ E2, float* __restrict__ wall,
                       float* __restrict__ Hq, float* __restrict__ Hb,
                       float* __restrict__ pgacc, unsigned* __restrict__ bar){
  int idx = blockIdx.x * 256 + threadIdx.x;
  if (idx < NC4){                                  // E2 = bf16(embed)
    float4 v = ((const float4*)embed)[idx];
    uint2 o;
    o.x = (unsigned)f2bf(v.x) | ((unsigned)f2bf(v.y) << 16);
    o.y = (unsigned)f2bf(v.z) | ((unsigned)f2bf(v.w) << 16);
    ((uint2*)E2)[idx] = o;
    return;
  }
  idx -= NC4;
  if (idx < NWALL){                                // W_all[t][b][k]
    int k  = idx % H_;
    int rb = idx / H_;
    int t = rb >> 5, b = rb & 31;
    int jj = t >> 3, kk = t & 7;
    float v;
    if (kk == 0) v = dec[(b*3 + jj)*H_ + k];
    else { int tok = teacher[(b*3 + jj)*8 + kk - 1]; v = embed[(size_t)tok*H_ + k]; }
    wall[idx] = v;
    return;
  }
  idx -= NWALL;
  if (idx < NINIT){                                // h0 -> Hb, Hq layouts
    int b = idx / H_, k = idx % H_;
    float v = hidden[idx];
    Hb[idx] = v;
    Hq[((k >> 1)*B_ + b)*2 + (k & 1)] = v;
    return;
  }
  idx -= NINIT;
  if (idx < 768){                                  // zero p_gen accumulator + barrier
    pgacc[idx] = 0.f;
    if (idx == 0) *bar = 0u;
  }
}

// ---------------- fp32 GEMM (NT) + bias:  gi^T = wall * wih^T + bih ----------------
// M=768, N=2304, K=768. Output layout giT[t][n][b] (b innermost) so the GRU's
// per-step reads are lane-contiguous.
__global__ __launch_bounds__(256) void k_gi_gemm(const float* __restrict__ A, const float* __restrict__ Bm,
                                                 const float* __restrict__ bias, float* __restrict__ C){
  __shared__ float As[16][68];
  __shared__ float Bs[16][68];
  const int tid = threadIdx.x;
  const int tx = tid & 15, ty = tid >> 4;
  const int m0 = blockIdx.x * 64, n0 = blockIdx.y * 64;
  const int r = tid >> 2, kq = tid & 3;
  float acc[4][4] = {};
  for (int k0 = 0; k0 < 768; k0 += 16){
    float4 av = *(const float4*)&A [(size_t)(m0 + r)*768 + k0 + kq*4];
    float4 bv = *(const float4*)&Bm[(size_t)(n0 + r)*768 + k0 + kq*4];
    __syncthreads();
    As[kq*4+0][r] = av.x; As[kq*4+1][r] = av.y; As[kq*4+2][r] = av.z; As[kq*4+3][r] = av.w;
    Bs[kq*4+0][r] = bv.x; Bs[kq*4+1][r] = bv.y; Bs[kq*4+2][r] = bv.z; Bs[kq*4+3][r] = bv.w;
    __syncthreads();
#pragma unroll
    for (int kk = 0; kk < 16; ++kk){
      float4 a4 = *(const float4*)&As[kk][ty*4];
      float4 b4 = *(const float4*)&Bs[kk][tx*4];
      float aa[4] = {a4.x, a4.y, a4.z, a4.w};
      float bb[4] = {b4.x, b4.y, b4.z, b4.w};
#pragma unroll
      for (int i = 0; i < 4; ++i)
#pragma unroll
        for (int j = 0; j < 4; ++j)
          acc[i][j] = fmaf(aa[i], bb[j], acc[i][j]);
    }
  }
#pragma unroll
  for (int i = 0; i < 4; ++i){
    int m = m0 + ty*4 + i;
    int t = m >> 5, b = m & 31;
#pragma unroll
    for (int j = 0; j < 4; ++j){
      int n = n0 + tx*4 + j;
      C[((size_t)t*H3 + n)*32 + b] = acc[i][j] + bias[n];
    }
  }
}

// ---------------- persistent GRU v4: fence-free coherent-point h exchange ----------------
// 192 blocks x 512 threads; weights (12 whh rows) in LDS. h_{t} is exchanged
// through agent-scope relaxed ATOMIC 64-bit loads/stores (sc0/sc1: bypass the
// non-coherent L1/L2, operate at the coherence point) -- NO cache-wide
// wbl2/inv fences anywhere, so gi + weights stay cache-warm. Ordering:
// __syncthreads() drains vmcnt before s_barrier, so stores complete before
// the counter increment, and loads issue only after the spin observes it.
// hp is carried in a register across steps (never re-read from memory).
__global__ __launch_bounds__(GRU_TPB) void k_gru_all(const float* __restrict__ gi, const float* __restrict__ whh,
                                                     const float* __restrict__ bhh, const float* __restrict__ hidden,
                                                     float* __restrict__ Hq, float* __restrict__ Hb,
                                                     ushort_t* __restrict__ A2, unsigned* __restrict__ bar){
  __shared__ float ws[GRU_RPB*768];        // 36864 B: [r][k], r = gate*4+jl
  __shared__ float red[16*392];            // 25088 B: [ks][r*32+b], stride 392
  __shared__ float bs[GRU_RPB];
  __shared__ float hn_st[128];
  const int tid = threadIdx.x;
  const int j0 = blockIdx.x * GRU_JPB;

  // one-time: stage this block's 12 whh rows + biases into LDS (float4, coalesced)
  for (int idx4 = tid; idx4 < GRU_RPB*192; idx4 += GRU_TPB){
    int r = idx4 / 192, k4 = idx4 % 192;
    int gate = r >> 2, jl = r & 3;
    *(float4*)&ws[r*768 + k4*4] = *(const float4*)&whh[(size_t)(gate*768 + j0 + jl)*768 + k4*4];
  }
  if (tid < GRU_RPB) bs[tid] = bhh[(tid >> 2)*768 + j0 + (tid & 3)];
  __syncthreads();

  const int ks = tid >> 5, b = tid & 31;   // compute mapping: 16 kslices x 32 batch
  const int jl = tid >> 5, bb = tid & 31;  // finalize mapping (tid < 128)
  const int j  = j0 + (jl & 3);
  float hp = 0.f;
  if (tid < 128) hp = hidden[bb*768 + j];  // h0 ([1,B,H] b-major), registered

  for (int t = 0; t < NT_; ++t){
    const unsigned long long* hsrc = (const unsigned long long*)(Hq + (size_t)t*24576);

    // prefetch finalize inputs early (gi stays L2-warm: no invalidations)
    float ir = 0.f, iz = 0.f, inn = 0.f;
    if (tid < 128){
      const float* gi_t = gi + (size_t)t*H3*32;
      ir  = gi_t[(size_t)(       j)*32 + bb];
      iz  = gi_t[(size_t)(768  + j)*32 + bb];
      inn = gi_t[(size_t)(1536 + j)*32 + bb];
    }

    // split-K dots: this thread's 48-k slice, all 12 rows; h via coherent atomics
    float acc[GRU_RPB];
#pragma unroll
    for (int r = 0; r < GRU_RPB; ++r) acc[r] = 0.f;
#pragma unroll 8
    for (int i = 0; i < 24; ++i){
      union { unsigned long long u; float f[2]; } cv;
      cv.u = __hip_atomic_load(&hsrc[(size_t)(ks*24 + i)*32 + b],
                               __ATOMIC_RELAXED, __HIP_MEMORY_SCOPE_AGENT);
      const float h0 = cv.f[0], h1 = cv.f[1];
#pragma unroll
      for (int r = 0; r < GRU_RPB; ++r){
        const float2 w2 = *(const float2*)&ws[r*768 + ks*48 + i*2];
        acc[r] += h0*w2.x + h1*w2.y;
      }
    }
#pragma unroll
    for (int r = 0; r < GRU_RPB; ++r) red[ks*392 + r*32 + b] = acc[r];
    __syncthreads();

    // finalize: 128 threads = 4 jl x 32 b
    if (tid < 128){
      float aR = 0.f, aZ = 0.f, aN = 0.f;
#pragma unroll
      for (int k8 = 0; k8 < 16; ++k8){
        aR += red[k8*392 + (0*GRU_JPB + jl)*32 + bb];
        aZ += red[k8*392 + (1*GRU_JPB + jl)*32 + bb];
        aN += red[k8*392 + (2*GRU_JPB + jl)*32 + bb];
      }
      aR += bs[jl]; aZ += bs[GRU_JPB + jl]; aN += bs[2*GRU_JPB + jl];
      float rg = 1.f / (1.f + __expf(-(ir + aR)));
      float zg = 1.f / (1.f + __expf(-(iz + aZ)));
      float e2 = __expf(-2.f*(inn + rg * aN));
      float ng = (1.f - e2) / (1.f + e2);
      float hn = (1.f - zg)*ng + zg*hp;
      hp = hn;                                            // carried in-register
      Hb[(size_t)(t+1)*24576 + bb*768 + j] = hn;          // plain (post-kernel consumers)
      A2[(size_t)(t*32 + bb)*768 + j] = f2bf(hn);         // plain (post-kernel consumer)
      hn_st[jl*32 + bb] = hn;
    }
    __syncthreads();

    if (t < NT_ - 1){
      // publish h_{t+1}: 64 threads (wave 0) pack pairs, agent-scope atomic store
      if (tid < 64){
        const int jp = tid >> 5, b2 = tid & 31;
        union { float f[2]; unsigned long long u; } cv;
        cv.f[0] = hn_st[(jp*2 + 0)*32 + b2];
        cv.f[1] = hn_st[(jp*2 + 1)*32 + b2];
        unsigned long long* hdst = (unsigned long long*)(Hq + (size_t)(t+1)*24576);
        __hip_atomic_store(&hdst[(size_t)(blockIdx.x*2 + jp)*32 + b2], cv.u,
                           __ATOMIC_RELAXED, __HIP_MEMORY_SCOPE_AGENT);
      }
      __syncthreads();                     // wave 0 drains vmcnt(0) before s_barrier
      if (tid == 0){
        __hip_atomic_fetch_add(bar, 1u, __ATOMIC_RELAXED, __HIP_MEMORY_SCOPE_AGENT);
        const unsigned tgt = (unsigned)(GRU_NBLK * (t + 1));
        unsigned spins = 0u;
        while (__hip_atomic_load(bar, __ATOMIC_RELAXED, __HIP_MEMORY_SCOPE_AGENT) < tgt &&
               ++spins < 20000000u)
          __builtin_amdgcn_s_sleep(2);
      }
      __syncthreads();
    }
  }
}

// ---------------- attn_e[t][b][s] = enc[b][s][:] . h[t+1][b][:]  (fp32) ----------------
__global__ __launch_bounds__(256) void k_attn(const float* __restrict__ enc, const float* __restrict__ Hb1,
                                              float* __restrict__ ae){
  __shared__ float Es[64*36];
  __shared__ float Ht[24*36];
  const int b = blockIdx.x, s0 = blockIdx.y * 64;
  const int tid = threadIdx.x;
  const int s_l = tid & 63, tq = tid >> 6;
  const int r = tid >> 2, kq = tid & 3;
  float acc[6] = {0.f,0.f,0.f,0.f,0.f,0.f};
  for (int k0 = 0; k0 < 768; k0 += 32){
    __syncthreads();
    float4 e0 = *(const float4*)&enc[(size_t)(b*512 + s0 + r)*768 + k0 + kq*8];
    float4 e1 = *(const float4*)&enc[(size_t)(b*512 + s0 + r)*768 + k0 + kq*8 + 4];
    *(float4*)&Es[r*36 + kq*8]     = e0;
    *(float4*)&Es[r*36 + kq*8 + 4] = e1;
    if (tid < 192){
      int t = tid >> 3, k4 = tid & 7;
      *(float4*)&Ht[t*36 + k4*4] = *(const float4*)&Hb1[(size_t)t*24576 + b*768 + k0 + k4*4];
    }
    __syncthreads();
#pragma unroll
    for (int k4 = 0; k4 < 8; ++k4){
      float4 e = *(const float4*)&Es[s_l*36 + k4*4];
#pragma unroll
      for (int i = 0; i < 6; ++i){
        float4 h4 = *(const float4*)&Ht[(tq*6 + i)*36 + k4*4];
        acc[i] += e.x*h4.x + e.y*h4.y + e.z*h4.z + e.w*h4.w;
      }
    }
  }
#pragma unroll
  for (int i = 0; i < 6; ++i)
    ae[(size_t)((tq*6 + i)*32 + b)*512 + s0 + s_l] = acc[i];
}

// ---------------- masked softmax over S=512, in place ----------------
__global__ __launch_bounds__(256) void k_attnsoft(const int* __restrict__ x, float* __restrict__ ae){
  const int row = blockIdx.x;            // t*32+b
  const int b = row & 31;
  const int tid = threadIdx.x;
  __shared__ float red[256];
  float v0 = ae[(size_t)row*512 + tid];
  float v1 = ae[(size_t)row*512 + 256 + tid];
  if (x[b*512 + tid]        == 0) v0 = -1e9f;
  if (x[b*512 + 256 + tid]  == 0) v1 = -1e9f;
  float m = fmaxf(v0, v1);
  red[tid] = m; __syncthreads();
  for (int off = 128; off; off >>= 1){ if (tid < off) red[tid] = fmaxf(red[tid], red[tid+off]); __syncthreads(); }
  float M = red[0]; __syncthreads();
  float e0 = __expf(v0 - M), e1 = __expf(v1 - M);
  red[tid] = e0 + e1; __syncthreads();
  for (int off = 128; off; off >>= 1){ if (tid < off) red[tid] += red[tid+off]; __syncthreads(); }
  float inv = 1.f / red[0];
  ae[(size_t)row*512 + tid]       = e0 * inv;
  ae[(size_t)row*512 + 256 + tid] = e1 * inv;
}

// ---------------- ctx reduction folded directly into p_gen partials ----------------
__global__ __launch_bounds__(256) void k_ctx_pgen(const float* __restrict__ enc, const float* __restrict__ ah,
                                                  const float* __restrict__ wall, const float* __restrict__ Hb1,
                                                  const float* __restrict__ wg, float* __restrict__ pgacc){
  const int b = blockIdx.x;
  const int klane = threadIdx.x & 63;
  const int k = blockIdx.y * 64 + klane;
  const int tq = threadIdx.x >> 6;
  float acc[6] = {0.f,0.f,0.f,0.f,0.f,0.f};
  for (int s4 = 0; s4 < 512; s4 += 4){
    float e0 = enc[(size_t)(b*512 + s4 + 0)*768 + k];
    float e1 = enc[(size_t)(b*512 + s4 + 1)*768 + k];
    float e2 = enc[(size_t)(b*512 + s4 + 2)*768 + k];
    float e3 = enc[(size_t)(b*512 + s4 + 3)*768 + k];
#pragma unroll
    for (int i = 0; i < 6; ++i){
      float4 a4 = *(const float4*)&ah[(size_t)((tq*6 + i)*32 + b)*512 + s4];
      acc[i] = fmaf(a4.x, e0, acc[i]); acc[i] = fmaf(a4.y, e1, acc[i]);
      acc[i] = fmaf(a4.z, e2, acc[i]); acc[i] = fmaf(a4.w, e3, acc[i]);
    }
  }
  const float wgk = wg[k], wgh = wg[768 + k], wgc = wg[1536 + k];
#pragma unroll
  for (int i = 0; i < 6; ++i){
    const int t = tq*6 + i, row = t*32 + b;
    float p = acc[i]*wgc + wall[(size_t)row*768 + k]*wgk + Hb1[(size_t)t*24576 + b*768 + k]*wgh;
#pragma unroll
    for (int off = 32; off; off >>= 1) p += __shfl_down(p, off, 64);
    if (klane == 0) atomicAdd(&pgacc[row], p);
  }
}

// ---------------- vocab logits GEMM (bf16 MFMA), XCD-grouped grid ----------------
// 1D grid 1440: the 6 m-tiles sharing an E2 n-panel land on the SAME XCD
// (round-robin heuristic), so each panel is HBM-fetched ~once chip-wide.
__global__ __launch_bounds__(256) void k_vgemm(const ushort_t* __restrict__ A2, const ushort_t* __restrict__ E2,
                                               float* __restrict__ out){
  __shared__ ushort_t ldsA[128*64];
  __shared__ ushort_t ldsB[128*64];
  const int wg = blockIdx.x;
  const int xcd = wg & 7, qq = wg >> 3;
  const int ntile = (qq / 6) * 8 + xcd;     // 0..239 (239 = all-OOB dummy)
  const int mtile = qq % 6;
  const int tid = threadIdx.x;
  const int w = tid >> 6, lane = tid & 63;
  const int lrow = lane >> 3, lpos = lane & 7;
  const int wm = w >> 1, wn = w & 1;
  const int q = lane >> 4, fr = lane & 15;
  f32x4 acc[4][4];
  f32x4 zero = {0.f, 0.f, 0.f, 0.f};
#pragma unroll
  for (int a = 0; a < 4; ++a)
#pragma unroll
    for (int c = 0; c < 4; ++c) acc[a][c] = zero;

  for (int k0 = 0; k0 < 768; k0 += 64){
    __syncthreads();
#pragma unroll
    for (int i = 0; i < 4; ++i){
      int row = w*32 + i*8 + lrow;          // 0..127
      int c   = lpos ^ (row & 7);           // XOR-swizzled source chunk
      const ushort_t* srcA = A2 + (size_t)(mtile*128 + row)*768 + k0 + c*8;
      int brow = ntile*128 + row; if (brow > V_ - 1) brow = V_ - 1;
      const ushort_t* srcB = E2 + (size_t)brow*768 + k0 + c*8;
      load_lds_16B(srcA, &ldsA[row*64 + lpos*8]);
      load_lds_16B(srcB, &ldsB[row*64 + lpos*8]);
    }
    __builtin_amdgcn_s_waitcnt(0);
    __syncthreads();
#pragma unroll
    for (int s = 0; s < 2; ++s){
      bf16x8 af[4], bfr[4];
#pragma unroll
      for (int mt = 0; mt < 4; ++mt){
        int row = wm*64 + mt*16 + fr;
        int ch = (s*4 + q) ^ (row & 7);
        af[mt] = *(const bf16x8*)&ldsA[row*64 + ch*8];
      }
#pragma unroll
      for (int nt = 0; nt < 4; ++nt){
        int row = wn*64 + nt*16 + fr;
        int ch = (s*4 + q) ^ (row & 7);
        bfr[nt] = *(const bf16x8*)&ldsB[row*64 + ch*8];
      }
#pragma unroll
      for (int mt = 0; mt < 4; ++mt)
#pragma unroll
        for (int nt = 0; nt < 4; ++nt)
          acc[mt][nt] = __builtin_amdgcn_mfma_f32_16x16x32_bf16(af[mt], bfr[nt], acc[mt][nt], 0, 0, 0);
    }
  }
#pragma unroll
  for (int mt = 0; mt < 4; ++mt){
#pragma unroll
    for (int nt = 0; nt < 4; ++nt){
      int gn = ntile*128 + wn*64 + nt*16 + fr;
      if (gn >= V_) continue;
#pragma unroll
      for (int rg = 0; rg < 4; ++rg){
        int gm = mtile*128 + wm*64 + mt*16 + q*4 + rg;   // A row = t*32+b
        int t = gm >> 5, b = gm & 31;
        out[(size_t)(b*24 + t)*V_ + gn] = acc[mt][nt][rg];
      }
    }
  }
}

// ---------------- vocab softmax (online) * p_gen, in place ----------------
__global__ __launch_bounds__(512) void k_vsoft(float* __restrict__ out, const float* __restrict__ pgacc,
                                               const float* __restrict__ wgb){
  const int row = blockIdx.x;            // b*24+t
  const int b = row / 24, t = row % 24;
  const float pg = 1.f / (1.f + __expf(-(pgacc[t*32 + b] + wgb[0])));
  const int tid = threadIdx.x;
  float* rp = out + (size_t)row * V_;
  const float4* rp4 = (const float4*)rp;
  float m = -3.0e38f, s = 0.f;
  for (int i = tid; i < 7630; i += 512){
    float4 v = rp4[i];
    float vm = fmaxf(fmaxf(v.x, v.y), fmaxf(v.z, v.w));
    float vs = __expf(v.x - vm) + __expf(v.y - vm) + __expf(v.z - vm) + __expf(v.w - vm);
    float nm = fmaxf(m, vm);
    s = s * __expf(m - nm) + vs * __expf(vm - nm);
    m = nm;
  }
  if (tid < 2){
    float v = rp[30520 + tid];
    float nm = fmaxf(m, v);
    s = s * __expf(m - nm) + __expf(v - nm);
    m = nm;
  }
#pragma unroll
  for (int off = 1; off < 64; off <<= 1){
    float m2 = __shfl_xor(m, off, 64), s2 = __shfl_xor(s, off, 64);
    float nm = fmaxf(m, m2);
    s = s*__expf(m - nm) + s2*__expf(m2 - nm);
    m = nm;
  }
  __shared__ float rm[8], rs[8];
  const int wid = tid >> 6;
  if ((tid & 63) == 0){ rm[wid] = m; rs[wid] = s; }
  __syncthreads();
  if (tid == 0){
    float M = rm[0], S = rs[0];
#pragma unroll
    for (int i = 1; i < 8; ++i){
      float m2 = rm[i], s2 = rs[i];
      float nm = fmaxf(M, m2);
      S = S*__expf(M - nm) + s2*__expf(m2 - nm);
      M = nm;
    }
    rm[0] = M; rs[0] = pg / S;
  }
  __syncthreads();
  const float M = rm[0], inv = rs[0];
  for (int i = tid; i < 7630; i += 512){
    float4 v = rp4[i];
    v.x = __expf(v.x - M) * inv;
    v.y = __expf(v.y - M) * inv;
    v.z = __expf(v.z - M) * inv;
    v.w = __expf(v.w - M) * inv;
    ((float4*)rp)[i] = v;
  }
  if (tid < 2) rp[30520 + tid] = __expf(rp[30520 + tid] - M) * inv;
}

// ---------------- scatter copy-distribution (separate kernel: boundary coherence) ----------------
__global__ void k_scatter(const float* __restrict__ ah, const float* __restrict__ pgacc,
                          const float* __restrict__ wgb, const int* __restrict__ x,
                          float* __restrict__ out){
  int idx = blockIdx.x * 256 + threadIdx.x;       // over 24*32*512
  int s = idx & 511;
  int row = idx >> 9;                              // t*32+b
  int t = row >> 5, b = row & 31;
  float pg = 1.f / (1.f + __expf(-(pgacc[row] + wgb[0])));
  float val = ah[idx] * (1.f - pg);
  int col = x[b*512 + s];
  atomicAdd(&out[(size_t)(b*24 + t)*V_ + col], val);
}

extern "C" void kernel_launch(void* const* d_in, const int* in_sizes, int n_in,
                              void* d_out, int out_size, void* d_ws, size_t ws_size,
                              hipStream_t stream){
  (void)in_sizes; (void)n_in; (void)out_size; (void)ws_size;
  const int*   x      = (const int*)  d_in[0];
  const float* dec    = (const float*)d_in[1];
  const float* enc    = (const float*)d_in[2];
  const float* hidden = (const float*)d_in[3];
  const int*   teach  = (const int*)  d_in[4];
  const float* embed  = (const float*)d_in[5];
  const float* wih    = (const float*)d_in[6];
  const float* whh    = (const float*)d_in[7];
  const float* bih    = (const float*)d_in[8];
  const float* bhh    = (const float*)d_in[9];
  const float* wg     = (const float*)d_in[10];
  const float* wgb    = (const float*)d_in[11];
  float* out = (float*)d_out;

  char* p = (char*)d_ws;
  auto alloc = [&](size_t bytes){ void* r = (void*)p; p += (bytes + 255) & ~(size_t)255; return r; };
  ushort_t* E2  = (ushort_t*)alloc((size_t)V_ * H_ * 2);            // 46.9 MB
  ushort_t* A2  = (ushort_t*)alloc((size_t)768 * 768 * 2);          // 1.2 MB
  float* wall   = (float*)alloc((size_t)NT_ * B_ * H_ * 4);         // 2.4 MB
  float* Hb     = (float*)alloc((size_t)(NT_+1) * B_ * H_ * 4);     // 2.5 MB
  float* Hq     = (float*)alloc((size_t)(NT_+1) * B_ * H_ * 4);     // 2.5 MB (pair layout)
  float* gi     = (float*)alloc((size_t)NT_ * B_ * H3 * 4);         // 7.1 MB (giT layout [t][n][b])
  float* ae     = (float*)alloc((size_t)NT_ * B_ * S_ * 4);         // 1.6 MB
  float* pgacc  = (float*)alloc(768 * 4);
  unsigned* bar = (unsigned*)alloc(256);

  const int prep_items  = NC4 + NWALL + NINIT + 768;
  const int prep_blocks = (prep_items + 255) / 256;

  // 9 dispatches
  k_prep<<<prep_blocks, 256, 0, stream>>>(embed, dec, teach, hidden, E2, wall, Hq, Hb, pgacc, bar);
  k_gi_gemm<<<dim3(12, 36), 256, 0, stream>>>(wall, wih, bih, gi);
  k_gru_all<<<GRU_NBLK, GRU_TPB, 0, stream>>>(gi, whh, bhh, hidden, Hq, Hb, A2, bar);
  k_attn<<<dim3(32, 8), 256, 0, stream>>>(enc, Hb + 24576, ae);
  k_attnsoft<<<768, 256, 0, stream>>>(x, ae);
  k_ctx_pgen<<<dim3(32, 12), 256, 0, stream>>>(enc, ae, wall, Hb + 24576, wg, pgacc);
  k_vgemm<<<1440, 256, 0, stream>>>(A2, E2, out);
  k_vsoft<<<768, 512, 0, stream>>>(out, pgacc, wgb);
  k_scatter<<<(NT_*B_*S_)/256, 256, 0, stream>>>(ae, pgacc, wgb, x, out);
}

// Round 5
// 731.245 us; speedup vs baseline: 1.8102x; 1.1256x over previous
//
#include <hip/hip_runtime.h>
#include <cstdint>

#define B_  32
#define S_  512
#define H_  768
#define V_  30522
#define NT_ 24          // N_UPDATE * MAX_LEN sequential steps
#define H3  2304
#define NC4   (V_*H_/4)           // 5860224 float4 casts for E2
#define NWALL (NT_*B_*H_)         // 589824
#define NINIT (B_*H_)             // 24576

#define GRU_NBLK 192
#define GRU_TPB  512
#define GRU_JPB  4                // j columns per block
#define GRU_RPB  12               // rows per block = 3 gates * GRU_JPB

typedef unsigned short ushort_t;
typedef __attribute__((ext_vector_type(8))) short bf16x8;
typedef __attribute__((ext_vector_type(4))) float f32x4;

__device__ __forceinline__ ushort_t f2bf(float f){
  union { float f; unsigned u; } v; v.f = f;
  unsigned r = v.u + 0x7fffu + ((v.u >> 16) & 1u);
  return (ushort_t)(r >> 16);
}

// ---------------- async global->LDS 16B helper ----------------
__device__ __forceinline__ void load_lds_16B(const void* g, void* l){
  auto gp = reinterpret_cast<const __attribute__((address_space(1))) unsigned int*>(
      reinterpret_cast<uintptr_t>(g));
  auto lp = reinterpret_cast<__attribute__((address_space(3))) unsigned int*>(
      reinterpret_cast<uintptr_t>(l));
  __builtin_amdgcn_global_load_lds(gp, lp, 16, 0, 0);
}

// ---------------- fused prep: E2 cast + W_all build + h0 init + zeroing ----------------
// Hq layout (pair-major for 64-bit atomic reads): Hq[((k>>1)*32 + b)*2 + (k&1)].
__global__ void k_prep(const float* __restrict__ embed, const float* __restrict__ dec,
                       const int* __restrict__ teacher, const float* __restrict__ hidden,
                       ushort_t* __restrict__ E2, float* __restrict__ wall,
                       float* __restrict__ Hq, float* __restrict__ Hb,
                       float* __restrict__ pgacc, unsigned* __restrict__ flags){
  int idx = blockIdx.x * 256 + threadIdx.x;
  if (idx < NC4){                                  // E2 = bf16(embed)
    float4 v = ((const float4*)embed)[idx];
    uint2 o;
    o.x = (unsigned)f2bf(v.x) | ((unsigned)f2bf(v.y) << 16);
    o.y = (unsigned)f2bf(v.z) | ((unsigned)f2bf(v.w) << 16);
    ((uint2*)E2)[idx] = o;
    return;
  }
  idx -= NC4;
  if (idx < NWALL){                                // W_all[t][b][k]
    int k  = idx % H_;
    int rb = idx / H_;
    int t = rb >> 5, b = rb & 31;
    int jj = t >> 3, kk = t & 7;
    float v;
    if (kk == 0) v = dec[(b*3 + jj)*H_ + k];
    else { int tok = teacher[(b*3 + jj)*8 + kk - 1]; v = embed[(size_t)tok*H_ + k]; }
    wall[idx] = v;
    return;
  }
  idx -= NWALL;
  if (idx < NINIT){                                // h0 -> Hb, Hq layouts
    int b = idx / H_, k = idx % H_;
    float v = hidden[idx];
    Hb[idx] = v;
    Hq[((k >> 1)*B_ + b)*2 + (k & 1)] = v;
    return;
  }
  idx -= NINIT;
  if (idx < 768){ pgacc[idx] = 0.f; return; }      // zero p_gen accumulator
  idx -= 768;
  if (idx < 768) flags[idx] = 0u;                  // zero arrival flags (192 x 16B)
}

// ---------------- fp32 GEMM (NT) + bias:  gi^T = wall * wih^T + bih ----------------
// M=768, N=2304, K=768. Output layout giT[t][n][b] (b innermost) so the GRU's
// per-step reads are lane-contiguous.
__global__ __launch_bounds__(256) void k_gi_gemm(const float* __restrict__ A, const float* __restrict__ Bm,
                                                 const float* __restrict__ bias, float* __restrict__ C){
  __shared__ float As[16][68];
  __shared__ float Bs[16][68];
  const int tid = threadIdx.x;
  const int tx = tid & 15, ty = tid >> 4;
  const int m0 = blockIdx.x * 64, n0 = blockIdx.y * 64;
  const int r = tid >> 2, kq = tid & 3;
  float acc[4][4] = {};
  for (int k0 = 0; k0 < 768; k0 += 16){
    float4 av = *(const float4*)&A [(size_t)(m0 + r)*768 + k0 + kq*4];
    float4 bv = *(const float4*)&Bm[(size_t)(n0 + r)*768 + k0 + kq*4];
    __syncthreads();
    As[kq*4+0][r] = av.x; As[kq*4+1][r] = av.y; As[kq*4+2][r] = av.z; As[kq*4+3][r] = av.w;
    Bs[kq*4+0][r] = bv.x; Bs[kq*4+1][r] = bv.y; Bs[kq*4+2][r] = bv.z; Bs[kq*4+3][r] = bv.w;
    __syncthreads();
#pragma unroll
    for (int kk = 0; kk < 16; ++kk){
      float4 a4 = *(const float4*)&As[kk][ty*4];
      float4 b4 = *(const float4*)&Bs[kk][tx*4];
      float aa[4] = {a4.x, a4.y, a4.z, a4.w};
      float bb[4] = {b4.x, b4.y, b4.z, b4.w};
#pragma unroll
      for (int i = 0; i < 4; ++i)
#pragma unroll
        for (int j = 0; j < 4; ++j)
          acc[i][j] = fmaf(aa[i], bb[j], acc[i][j]);
    }
  }
#pragma unroll
  for (int i = 0; i < 4; ++i){
    int m = m0 + ty*4 + i;
    int t = m >> 5, b = m & 31;
#pragma unroll
    for (int j = 0; j < 4; ++j){
      int n = n0 + tx*4 + j;
      C[((size_t)t*H3 + n)*32 + b] = acc[i][j] + bias[n];
    }
  }
}

// ---------------- persistent GRU v5: flag-array barrier, direct h publish ----------------
// 192 blocks x 512 threads; weights (12 whh rows) in LDS. h exchanged via
// agent-scope relaxed atomics at the coherence point (no cache-wide fences).
// Arrival barrier = per-block FLAG STORE (no contended RMW) + 192-thread
// parallel poll of distinct flags. Finalize threads publish hn directly
// (32-bit atomic stores); readers use 64-bit pair loads. Ordering:
// __syncthreads() per-wave vmcnt(0) drain between h stores and flag store;
// poll-hit precedes next step's h loads. Spin bounded => no hard hang.
__global__ __launch_bounds__(GRU_TPB) void k_gru_all(const float* __restrict__ gi, const float* __restrict__ whh,
                                                     const float* __restrict__ bhh, const float* __restrict__ hidden,
                                                     float* __restrict__ Hq, float* __restrict__ Hb,
                                                     ushort_t* __restrict__ A2, unsigned* __restrict__ flags){
  __shared__ float ws[GRU_RPB*768];        // 36864 B: [r][k], r = gate*4+jl
  __shared__ float red[16*392];            // 25088 B: [ks][r*32+b], stride 392
  __shared__ float bs[GRU_RPB];
  const int tid = threadIdx.x;
  const int j0 = blockIdx.x * GRU_JPB;

  // one-time: stage this block's 12 whh rows + biases into LDS (float4, coalesced)
  for (int idx4 = tid; idx4 < GRU_RPB*192; idx4 += GRU_TPB){
    int r = idx4 / 192, k4 = idx4 % 192;
    int gate = r >> 2, jl = r & 3;
    *(float4*)&ws[r*768 + k4*4] = *(const float4*)&whh[(size_t)(gate*768 + j0 + jl)*768 + k4*4];
  }
  if (tid < GRU_RPB) bs[tid] = bhh[(tid >> 2)*768 + j0 + (tid & 3)];
  __syncthreads();

  const int ks = tid >> 5, b = tid & 31;   // compute mapping: 16 kslices x 32 batch
  const int jl = tid >> 5, bb = tid & 31;  // finalize mapping (tid < 128)
  const int j  = j0 + (jl & 3);
  float hp = 0.f;
  if (tid < 128) hp = hidden[bb*768 + j];  // h0 ([1,B,H] b-major), registered

  for (int t = 0; t < NT_; ++t){
    const unsigned long long* hsrc = (const unsigned long long*)(Hq + (size_t)t*24576);

    // prefetch finalize inputs early (gi stays L2-warm: nothing invalidates it)
    float ir = 0.f, iz = 0.f, inn = 0.f;
    if (tid < 128){
      const float* gi_t = gi + (size_t)t*H3*32;
      ir  = gi_t[(size_t)(       j)*32 + bb];
      iz  = gi_t[(size_t)(768  + j)*32 + bb];
      inn = gi_t[(size_t)(1536 + j)*32 + bb];
    }

    // split-K dots: this thread's 48-k slice, all 12 rows; h via coherent atomics
    float acc[GRU_RPB];
#pragma unroll
    for (int r = 0; r < GRU_RPB; ++r) acc[r] = 0.f;
#pragma unroll
    for (int i = 0; i < 24; ++i){
      union { unsigned long long u; float f[2]; } cv;
      cv.u = __hip_atomic_load(&hsrc[(size_t)(ks*24 + i)*32 + b],
                               __ATOMIC_RELAXED, __HIP_MEMORY_SCOPE_AGENT);
      const float h0 = cv.f[0], h1 = cv.f[1];
#pragma unroll
      for (int r = 0; r < GRU_RPB; ++r){
        const float2 w2 = *(const float2*)&ws[r*768 + ks*48 + i*2];
        acc[r] += h0*w2.x + h1*w2.y;
      }
    }
#pragma unroll
    for (int r = 0; r < GRU_RPB; ++r) red[ks*392 + r*32 + b] = acc[r];
    __syncthreads();

    // finalize: 128 threads = 4 jl x 32 b; publish hn directly
    if (tid < 128){
      float aR = 0.f, aZ = 0.f, aN = 0.f;
#pragma unroll
      for (int k8 = 0; k8 < 16; ++k8){
        aR += red[k8*392 + (0*GRU_JPB + jl)*32 + bb];
        aZ += red[k8*392 + (1*GRU_JPB + jl)*32 + bb];
        aN += red[k8*392 + (2*GRU_JPB + jl)*32 + bb];
      }
      aR += bs[jl]; aZ += bs[GRU_JPB + jl]; aN += bs[2*GRU_JPB + jl];
      float rg = 1.f / (1.f + __expf(-(ir + aR)));
      float zg = 1.f / (1.f + __expf(-(iz + aZ)));
      float e2 = __expf(-2.f*(inn + rg * aN));
      float ng = (1.f - e2) / (1.f + e2);
      float hn = (1.f - zg)*ng + zg*hp;
      hp = hn;                                            // carried in-register
      Hb[(size_t)(t+1)*24576 + bb*768 + j] = hn;          // plain (post-kernel consumers)
      A2[(size_t)(t*32 + bb)*768 + j] = f2bf(hn);         // plain (post-kernel consumer)
      if (t < NT_ - 1){
        union { float f; unsigned u; } hv; hv.f = hn;
        unsigned* hq32 = (unsigned*)(Hq + (size_t)(t+1)*24576);
        __hip_atomic_store(&hq32[((j >> 1)*32 + bb)*2 + (j & 1)], hv.u,
                           __ATOMIC_RELAXED, __HIP_MEMORY_SCOPE_AGENT);
      }
    }
    __syncthreads();                       // per-wave vmcnt(0): h stores complete

    if (t < NT_ - 1){
      if (tid == 0)
        __hip_atomic_store(&flags[(size_t)blockIdx.x*4], (unsigned)(t + 1),
                           __ATOMIC_RELAXED, __HIP_MEMORY_SCOPE_AGENT);
      if (tid < GRU_NBLK){                 // parallel poll: one distinct flag/thread
        unsigned spins = 0u;
        while (__hip_atomic_load(&flags[(size_t)tid*4], __ATOMIC_RELAXED,
                                 __HIP_MEMORY_SCOPE_AGENT) < (unsigned)(t + 1) &&
               ++spins < 20000000u)
          __builtin_amdgcn_s_sleep(1);
      }
      __syncthreads();
    }
  }
}

// ---------------- attn_e[t][b][s] = enc[b][s][:] . h[t+1][b][:]  (fp32) ----------------
__global__ __launch_bounds__(256) void k_attn(const float* __restrict__ enc, const float* __restrict__ Hb1,
                                              float* __restrict__ ae){
  __shared__ float Es[64*36];
  __shared__ float Ht[24*36];
  const int b = blockIdx.x, s0 = blockIdx.y * 64;
  const int tid = threadIdx.x;
  const int s_l = tid & 63, tq = tid >> 6;
  const int r = tid >> 2, kq = tid & 3;
  float acc[6] = {0.f,0.f,0.f,0.f,0.f,0.f};
  for (int k0 = 0; k0 < 768; k0 += 32){
    __syncthreads();
    float4 e0 = *(const float4*)&enc[(size_t)(b*512 + s0 + r)*768 + k0 + kq*8];
    float4 e1 = *(const float4*)&enc[(size_t)(b*512 + s0 + r)*768 + k0 + kq*8 + 4];
    *(float4*)&Es[r*36 + kq*8]     = e0;
    *(float4*)&Es[r*36 + kq*8 + 4] = e1;
    if (tid < 192){
      int t = tid >> 3, k4 = tid & 7;
      *(float4*)&Ht[t*36 + k4*4] = *(const float4*)&Hb1[(size_t)t*24576 + b*768 + k0 + k4*4];
    }
    __syncthreads();
#pragma unroll
    for (int k4 = 0; k4 < 8; ++k4){
      float4 e = *(const float4*)&Es[s_l*36 + k4*4];
#pragma unroll
      for (int i = 0; i < 6; ++i){
        float4 h4 = *(const float4*)&Ht[(tq*6 + i)*36 + k4*4];
        acc[i] += e.x*h4.x + e.y*h4.y + e.z*h4.z + e.w*h4.w;
      }
    }
  }
#pragma unroll
  for (int i = 0; i < 6; ++i)
    ae[(size_t)((tq*6 + i)*32 + b)*512 + s0 + s_l] = acc[i];
}

// ---------------- masked softmax over S=512, in place ----------------
__global__ __launch_bounds__(256) void k_attnsoft(const int* __restrict__ x, float* __restrict__ ae){
  const int row = blockIdx.x;            // t*32+b
  const int b = row & 31;
  const int tid = threadIdx.x;
  __shared__ float red[256];
  float v0 = ae[(size_t)row*512 + tid];
  float v1 = ae[(size_t)row*512 + 256 + tid];
  if (x[b*512 + tid]        == 0) v0 = -1e9f;
  if (x[b*512 + 256 + tid]  == 0) v1 = -1e9f;
  float m = fmaxf(v0, v1);
  red[tid] = m; __syncthreads();
  for (int off = 128; off; off >>= 1){ if (tid < off) red[tid] = fmaxf(red[tid], red[tid+off]); __syncthreads(); }
  float M = red[0]; __syncthreads();
  float e0 = __expf(v0 - M), e1 = __expf(v1 - M);
  red[tid] = e0 + e1; __syncthreads();
  for (int off = 128; off; off >>= 1){ if (tid < off) red[tid] += red[tid+off]; __syncthreads(); }
  float inv = 1.f / red[0];
  ae[(size_t)row*512 + tid]       = e0 * inv;
  ae[(size_t)row*512 + 256 + tid] = e1 * inv;
}

// ---------------- ctx reduction folded directly into p_gen partials ----------------
__global__ __launch_bounds__(256) void k_ctx_pgen(const float* __restrict__ enc, const float* __restrict__ ah,
                                                  const float* __restrict__ wall, const float* __restrict__ Hb1,
                                                  const float* __restrict__ wg, float* __restrict__ pgacc){
  const int b = blockIdx.x;
  const int klane = threadIdx.x & 63;
  const int k = blockIdx.y * 64 + klane;
  const int tq = threadIdx.x >> 6;
  float acc[6] = {0.f,0.f,0.f,0.f,0.f,0.f};
  for (int s4 = 0; s4 < 512; s4 += 4){
    float e0 = enc[(size_t)(b*512 + s4 + 0)*768 + k];
    float e1 = enc[(size_t)(b*512 + s4 + 1)*768 + k];
    float e2 = enc[(size_t)(b*512 + s4 + 2)*768 + k];
    float e3 = enc[(size_t)(b*512 + s4 + 3)*768 + k];
#pragma unroll
    for (int i = 0; i < 6; ++i){
      float4 a4 = *(const float4*)&ah[(size_t)((tq*6 + i)*32 + b)*512 + s4];
      acc[i] = fmaf(a4.x, e0, acc[i]); acc[i] = fmaf(a4.y, e1, acc[i]);
      acc[i] = fmaf(a4.z, e2, acc[i]); acc[i] = fmaf(a4.w, e3, acc[i]);
    }
  }
  const float wgk = wg[k], wgh = wg[768 + k], wgc = wg[1536 + k];
#pragma unroll
  for (int i = 0; i < 6; ++i){
    const int t = tq*6 + i, row = t*32 + b;
    float p = acc[i]*wgc + wall[(size_t)row*768 + k]*wgk + Hb1[(size_t)t*24576 + b*768 + k]*wgh;
#pragma unroll
    for (int off = 32; off; off >>= 1) p += __shfl_down(p, off, 64);
    if (klane == 0) atomicAdd(&pgacc[row], p);
  }
}

// ---------------- vocab logits GEMM (bf16 MFMA), XCD-grouped grid ----------------
__global__ __launch_bounds__(256) void k_vgemm(const ushort_t* __restrict__ A2, const ushort_t* __restrict__ E2,
                                               float* __restrict__ out){
  __shared__ ushort_t ldsA[128*64];
  __shared__ ushort_t ldsB[128*64];
  const int wg = blockIdx.x;
  const int xcd = wg & 7, qq = wg >> 3;
  const int ntile = (qq / 6) * 8 + xcd;     // 0..239 (239 = all-OOB dummy)
  const int mtile = qq % 6;
  const int tid = threadIdx.x;
  const int w = tid >> 6, lane = tid & 63;
  const int lrow = lane >> 3, lpos = lane & 7;
  const int wm = w >> 1, wn = w & 1;
  const int q = lane >> 4, fr = lane & 15;
  f32x4 acc[4][4];
  f32x4 zero = {0.f, 0.f, 0.f, 0.f};
#pragma unroll
  for (int a = 0; a < 4; ++a)
#pragma unroll
    for (int c = 0; c < 4; ++c) acc[a][c] = zero;

  for (int k0 = 0; k0 < 768; k0 += 64){
    __syncthreads();
#pragma unroll
    for (int i = 0; i < 4; ++i){
      int row = w*32 + i*8 + lrow;          // 0..127
      int c   = lpos ^ (row & 7);           // XOR-swizzled source chunk
      const ushort_t* srcA = A2 + (size_t)(mtile*128 + row)*768 + k0 + c*8;
      int brow = ntile*128 + row; if (brow > V_ - 1) brow = V_ - 1;
      const ushort_t* srcB = E2 + (size_t)brow*768 + k0 + c*8;
      load_lds_16B(srcA, &ldsA[row*64 + lpos*8]);
      load_lds_16B(srcB, &ldsB[row*64 + lpos*8]);
    }
    __builtin_amdgcn_s_waitcnt(0);
    __syncthreads();
#pragma unroll
    for (int s = 0; s < 2; ++s){
      bf16x8 af[4], bfr[4];
#pragma unroll
      for (int mt = 0; mt < 4; ++mt){
        int row = wm*64 + mt*16 + fr;
        int ch = (s*4 + q) ^ (row & 7);
        af[mt] = *(const bf16x8*)&ldsA[row*64 + ch*8];
      }
#pragma unroll
      for (int nt = 0; nt < 4; ++nt){
        int row = wn*64 + nt*16 + fr;
        int ch = (s*4 + q) ^ (row & 7);
        bfr[nt] = *(const bf16x8*)&ldsB[row*64 + ch*8];
      }
#pragma unroll
      for (int mt = 0; mt < 4; ++mt)
#pragma unroll
        for (int nt = 0; nt < 4; ++nt)
          acc[mt][nt] = __builtin_amdgcn_mfma_f32_16x16x32_bf16(af[mt], bfr[nt], acc[mt][nt], 0, 0, 0);
    }
  }
#pragma unroll
  for (int mt = 0; mt < 4; ++mt){
#pragma unroll
    for (int nt = 0; nt < 4; ++nt){
      int gn = ntile*128 + wn*64 + nt*16 + fr;
      if (gn >= V_) continue;
#pragma unroll
      for (int rg = 0; rg < 4; ++rg){
        int gm = mtile*128 + wm*64 + mt*16 + q*4 + rg;   // A row = t*32+b
        int t = gm >> 5, b = gm & 31;
        out[(size_t)(b*24 + t)*V_ + gn] = acc[mt][nt][rg];
      }
    }
  }
}

// ---------------- vocab softmax (online) * p_gen, in place ----------------
__global__ __launch_bounds__(512) void k_vsoft(float* __restrict__ out, const float* __restrict__ pgacc,
                                               const float* __restrict__ wgb){
  const int row = blockIdx.x;            // b*24+t
  const int b = row / 24, t = row % 24;
  const float pg = 1.f / (1.f + __expf(-(pgacc[t*32 + b] + wgb[0])));
  const int tid = threadIdx.x;
  float* rp = out + (size_t)row * V_;
  const float4* rp4 = (const float4*)rp;
  float m = -3.0e38f, s = 0.f;
  for (int i = tid; i < 7630; i += 512){
    float4 v = rp4[i];
    float vm = fmaxf(fmaxf(v.x, v.y), fmaxf(v.z, v.w));
    float vs = __expf(v.x - vm) + __expf(v.y - vm) + __expf(v.z - vm) + __expf(v.w - vm);
    float nm = fmaxf(m, vm);
    s = s * __expf(m - nm) + vs * __expf(vm - nm);
    m = nm;
  }
  if (tid < 2){
    float v = rp[30520 + tid];
    float nm = fmaxf(m, v);
    s = s * __expf(m - nm) + __expf(v - nm);
    m = nm;
  }
#pragma unroll
  for (int off = 1; off < 64; off <<= 1){
    float m2 = __shfl_xor(m, off, 64), s2 = __shfl_xor(s, off, 64);
    float nm = fmaxf(m, m2);
    s = s*__expf(m - nm) + s2*__expf(m2 - nm);
    m = nm;
  }
  __shared__ float rm[8], rs[8];
  const int wid = tid >> 6;
  if ((tid & 63) == 0){ rm[wid] = m; rs[wid] = s; }
  __syncthreads();
  if (tid == 0){
    float M = rm[0], S = rs[0];
#pragma unroll
    for (int i = 1; i < 8; ++i){
      float m2 = rm[i], s2 = rs[i];
      float nm = fmaxf(M, m2);
      S = S*__expf(M - nm) + s2*__expf(m2 - nm);
      M = nm;
    }
    rm[0] = M; rs[0] = pg / S;
  }
  __syncthreads();
  const float M = rm[0], inv = rs[0];
  for (int i = tid; i < 7630; i += 512){
    float4 v = rp4[i];
    v.x = __expf(v.x - M) * inv;
    v.y = __expf(v.y - M) * inv;
    v.z = __expf(v.z - M) * inv;
    v.w = __expf(v.w - M) * inv;
    ((float4*)rp)[i] = v;
  }
  if (tid < 2) rp[30520 + tid] = __expf(rp[30520 + tid] - M) * inv;
}

// ---------------- scatter copy-distribution (separate kernel: boundary coherence) ----------------
__global__ void k_scatter(const float* __restrict__ ah, const float* __restrict__ pgacc,
                          const float* __restrict__ wgb, const int* __restrict__ x,
                          float* __restrict__ out){
  int idx = blockIdx.x * 256 + threadIdx.x;       // over 24*32*512
  int s = idx & 511;
  int row = idx >> 9;                              // t*32+b
  int t = row >> 5, b = row & 31;
  float pg = 1.f / (1.f + __expf(-(pgacc[row] + wgb[0])));
  float val = ah[idx] * (1.f - pg);
  int col = x[b*512 + s];
  atomicAdd(&out[(size_t)(b*24 + t)*V_ + col], val);
}

extern "C" void kernel_launch(void* const* d_in, const int* in_sizes, int n_in,
                              void* d_out, int out_size, void* d_ws, size_t ws_size,
                              hipStream_t stream){
  (void)in_sizes; (void)n_in; (void)out_size; (void)ws_size;
  const int*   x      = (const int*)  d_in[0];
  const float* dec    = (const float*)d_in[1];
  const float* enc    = (const float*)d_in[2];
  const float* hidden = (const float*)d_in[3];
  const int*   teach  = (const int*)  d_in[4];
  const float* embed  = (const float*)d_in[5];
  const float* wih    = (const float*)d_in[6];
  const float* whh    = (const float*)d_in[7];
  const float* bih    = (const float*)d_in[8];
  const float* bhh    = (const float*)d_in[9];
  const float* wg     = (const float*)d_in[10];
  const float* wgb    = (const float*)d_in[11];
  float* out = (float*)d_out;

  char* p = (char*)d_ws;
  auto alloc = [&](size_t bytes){ void* r = (void*)p; p += (bytes + 255) & ~(size_t)255; return r; };
  ushort_t* E2  = (ushort_t*)alloc((size_t)V_ * H_ * 2);            // 46.9 MB
  ushort_t* A2  = (ushort_t*)alloc((size_t)768 * 768 * 2);          // 1.2 MB
  float* wall   = (float*)alloc((size_t)NT_ * B_ * H_ * 4);         // 2.4 MB
  float* Hb     = (float*)alloc((size_t)(NT_+1) * B_ * H_ * 4);     // 2.5 MB
  float* Hq     = (float*)alloc((size_t)(NT_+1) * B_ * H_ * 4);     // 2.5 MB (pair layout)
  float* gi     = (float*)alloc((size_t)NT_ * B_ * H3 * 4);         // 7.1 MB (giT layout [t][n][b])
  float* ae     = (float*)alloc((size_t)NT_ * B_ * S_ * 4);         // 1.6 MB
  float* pgacc  = (float*)alloc(768 * 4);
  unsigned* flags = (unsigned*)alloc(768 * 4);                      // 192 flags, 16B stride

  const int prep_items  = NC4 + NWALL + NINIT + 768 + 768;
  const int prep_blocks = (prep_items + 255) / 256;

  // 9 dispatches
  k_prep<<<prep_blocks, 256, 0, stream>>>(embed, dec, teach, hidden, E2, wall, Hq, Hb, pgacc, flags);
  k_gi_gemm<<<dim3(12, 36), 256, 0, stream>>>(wall, wih, bih, gi);
  k_gru_all<<<GRU_NBLK, GRU_TPB, 0, stream>>>(gi, whh, bhh, hidden, Hq, Hb, A2, flags);
  k_attn<<<dim3(32, 8), 256, 0, stream>>>(enc, Hb + 24576, ae);
  k_attnsoft<<<768, 256, 0, stream>>>(x, ae);
  k_ctx_pgen<<<dim3(32, 12), 256, 0, stream>>>(enc, ae, wall, Hb + 24576, wg, pgacc);
  k_vgemm<<<1440, 256, 0, stream>>>(A2, E2, out);
  k_vsoft<<<768, 512, 0, stream>>>(out, pgacc, wgb);
  k_scatter<<<(NT_*B_*S_)/256, 256, 0, stream>>>(ae, pgacc, wgb, x, out);
}

// Round 6
// 706.377 us; speedup vs baseline: 1.8739x; 1.0352x over previous
//
#include <hip/hip_runtime.h>
#include <cstdint>

#define B_  32
#define S_  512
#define H_  768
#define V_  30522
#define NT_ 24          // N_UPDATE * MAX_LEN sequential steps
#define H3  2304
#define NC4   (V_*H_/4)           // 5860224 float4 casts for E2
#define NWALL (NT_*B_*H_)         // 589824
#define NINIT (B_*H_)             // 24576

#define GRU_NBLK 192
#define GRU_TPB  512
#define GRU_JPB  4                // j columns per block
#define GRU_RPB  12               // rows per block = 3 gates * GRU_JPB

typedef unsigned short ushort_t;
typedef __attribute__((ext_vector_type(8))) short bf16x8;
typedef __attribute__((ext_vector_type(4))) float f32x4;

__device__ __forceinline__ ushort_t f2bf(float f){
  union { float f; unsigned u; } v; v.f = f;
  unsigned r = v.u + 0x7fffu + ((v.u >> 16) & 1u);
  return (ushort_t)(r >> 16);
}

// ---------------- async global->LDS 16B helper ----------------
__device__ __forceinline__ void load_lds_16B(const void* g, void* l){
  auto gp = reinterpret_cast<const __attribute__((address_space(1))) unsigned int*>(
      reinterpret_cast<uintptr_t>(g));
  auto lp = reinterpret_cast<__attribute__((address_space(3))) unsigned int*>(
      reinterpret_cast<uintptr_t>(l));
  __builtin_amdgcn_global_load_lds(gp, lp, 16, 0, 0);
}

// ---------------- fused prep: E2 cast + W_all build (2 layouts) + h0 init + zeroing ----------------
// Hq pair layout: Hq[((k>>1)*32 + b)*2 + (k&1)]  (64-bit-atomic exchangeable)
// wallT pair layout: wallT[t*24576 + ((k>>1)*32 + b)*2 + (k&1)]  (coalesced GRU reads)
__global__ void k_prep(const float* __restrict__ embed, const float* __restrict__ dec,
                       const int* __restrict__ teacher, const float* __restrict__ hidden,
                       ushort_t* __restrict__ E2, float* __restrict__ wall,
                       float* __restrict__ wallT, float* __restrict__ Hq, float* __restrict__ Hb,
                       float* __restrict__ pgacc, unsigned* __restrict__ flags){
  int idx = blockIdx.x * 256 + threadIdx.x;
  if (idx < NC4){                                  // E2 = bf16(embed)
    float4 v = ((const float4*)embed)[idx];
    uint2 o;
    o.x = (unsigned)f2bf(v.x) | ((unsigned)f2bf(v.y) << 16);
    o.y = (unsigned)f2bf(v.z) | ((unsigned)f2bf(v.w) << 16);
    ((uint2*)E2)[idx] = o;
    return;
  }
  idx -= NC4;
  if (idx < NWALL){                                // W_all[t][b][k] (both layouts)
    int k  = idx % H_;
    int rb = idx / H_;
    int t = rb >> 5, b = rb & 31;
    int jj = t >> 3, kk = t & 7;
    float v;
    if (kk == 0) v = dec[(b*3 + jj)*H_ + k];
    else { int tok = teacher[(b*3 + jj)*8 + kk - 1]; v = embed[(size_t)tok*H_ + k]; }
    wall[idx] = v;                                              // [t*32+b][k] (ctx_pgen)
    wallT[(size_t)t*24576 + ((k >> 1)*B_ + b)*2 + (k & 1)] = v; // pair-major (GRU)
    return;
  }
  idx -= NWALL;
  if (idx < NINIT){                                // h0 -> Hb, Hq layouts
    int b = idx / H_, k = idx % H_;
    float v = hidden[idx];
    Hb[idx] = v;
    Hq[((k >> 1)*B_ + b)*2 + (k & 1)] = v;
    return;
  }
  idx -= NINIT;
  if (idx < 768){ pgacc[idx] = 0.f; return; }      // zero p_gen accumulator
  idx -= 768;
  if (idx < 768) flags[idx] = 0u;                  // zero arrival flags (192 x 16B)
}

// ---------------- persistent GRU v6: gi GEMM fused in, flag barrier, direct h publish ----------------
// 192 blocks x 512 threads; each block owns 4 j columns -> 12 whh rows AND
// 12 wih rows in LDS (73.7 KB). The split-K dot loop accumulates BOTH
// gh = whh.h_t (coherent atomic h loads) and gi = wih.w_t (plain cached
// wallT loads) in one pass -- k_gi_gemm and the 7.1 MB gi buffer are gone.
// Barrier = per-block flag store + 192-thread parallel poll (round-5 proven).
// LDS total ~120.6 KB (under the 128 KB proven-safe line).
__global__ __launch_bounds__(GRU_TPB) void k_gru_all(const float* __restrict__ wallT, const float* __restrict__ wih,
                                                     const float* __restrict__ whh, const float* __restrict__ bih,
                                                     const float* __restrict__ bhh, const float* __restrict__ hidden,
                                                     float* __restrict__ Hq, float* __restrict__ Hb,
                                                     ushort_t* __restrict__ A2, unsigned* __restrict__ flags){
  __shared__ float wsh[GRU_RPB*768];       // 36864 B: whh rows [r][k], r = gate*4+jl
  __shared__ float wsi[GRU_RPB*768];       // 36864 B: wih rows
  __shared__ float red[16*776];            // 49664 B: [ks][row*32+b], rows 0..11 hh / 12..23 ih
  __shared__ float bsh[GRU_RPB], bsi[GRU_RPB];
  const int tid = threadIdx.x;
  const int j0 = blockIdx.x * GRU_JPB;

  // one-time: stage weights + biases into LDS (float4, coalesced)
  for (int idx4 = tid; idx4 < GRU_RPB*192; idx4 += GRU_TPB){
    int r = idx4 / 192, k4 = idx4 % 192;
    int gate = r >> 2, jl = r & 3;
    *(float4*)&wsh[r*768 + k4*4] = *(const float4*)&whh[(size_t)(gate*768 + j0 + jl)*768 + k4*4];
    *(float4*)&wsi[r*768 + k4*4] = *(const float4*)&wih[(size_t)(gate*768 + j0 + jl)*768 + k4*4];
  }
  if (tid < GRU_RPB){
    bsh[tid] = bhh[(tid >> 2)*768 + j0 + (tid & 3)];
    bsi[tid] = bih[(tid >> 2)*768 + j0 + (tid & 3)];
  }
  __syncthreads();

  const int ks = tid >> 5, b = tid & 31;   // compute mapping: 16 kslices x 32 batch
  const int jl = tid >> 5, bb = tid & 31;  // finalize mapping (tid < 128)
  const int j  = j0 + (jl & 3);
  float hp = 0.f;
  if (tid < 128) hp = hidden[bb*768 + j];  // h0 ([1,B,H] b-major), registered

  for (int t = 0; t < NT_; ++t){
    const unsigned long long* hsrc = (const unsigned long long*)(Hq + (size_t)t*24576);
    const float2* wsrc = (const float2*)(wallT + (size_t)t*24576);

    // split-K dual dots: gh (coherent h) + gi (cached wallT), 12 rows each
    float acch[GRU_RPB], acci[GRU_RPB];
#pragma unroll
    for (int r = 0; r < GRU_RPB; ++r){ acch[r] = 0.f; acci[r] = 0.f; }
#pragma unroll 4
    for (int i = 0; i < 24; ++i){
      union { unsigned long long u; float f[2]; } cv;
      cv.u = __hip_atomic_load(&hsrc[(size_t)(ks*24 + i)*32 + b],
                               __ATOMIC_RELAXED, __HIP_MEMORY_SCOPE_AGENT);
      const float2 wv = wsrc[(size_t)(ks*24 + i)*32 + b];
      const float h0 = cv.f[0], h1 = cv.f[1];
#pragma unroll
      for (int r = 0; r < GRU_RPB; ++r){
        const float2 wh = *(const float2*)&wsh[r*768 + ks*48 + i*2];
        const float2 wi = *(const float2*)&wsi[r*768 + ks*48 + i*2];
        acch[r] += h0*wh.x + h1*wh.y;
        acci[r] += wv.x*wi.x + wv.y*wi.y;
      }
    }
#pragma unroll
    for (int r = 0; r < GRU_RPB; ++r){
      red[ks*776 + r*32 + b]             = acch[r];
      red[ks*776 + (GRU_RPB + r)*32 + b] = acci[r];
    }
    __syncthreads();

    // finalize: 128 threads = 4 jl x 32 b; publish hn directly
    if (tid < 128){
      float aR = 0.f, aZ = 0.f, aN = 0.f, iR = 0.f, iZ = 0.f, iN = 0.f;
#pragma unroll
      for (int k8 = 0; k8 < 16; ++k8){
        const float* rb_ = &red[k8*776 + jl*32 + bb];
        aR += rb_[0*128]; aZ += rb_[1*128]; aN += rb_[2*128];
        iR += rb_[3*128]; iZ += rb_[4*128]; iN += rb_[5*128];
      }
      aR += bsh[jl]; aZ += bsh[4 + jl]; aN += bsh[8 + jl];
      const float ir = iR + bsi[jl], iz = iZ + bsi[4 + jl], inn = iN + bsi[8 + jl];
      float rg = 1.f / (1.f + __expf(-(ir + aR)));
      float zg = 1.f / (1.f + __expf(-(iz + aZ)));
      float e2 = __expf(-2.f*(inn + rg * aN));
      float ng = (1.f - e2) / (1.f + e2);
      float hn = (1.f - zg)*ng + zg*hp;
      hp = hn;                                            // carried in-register
      Hb[(size_t)(t+1)*24576 + bb*768 + j] = hn;          // plain (post-kernel consumers)
      A2[(size_t)(t*32 + bb)*768 + j] = f2bf(hn);         // plain (post-kernel consumer)
      if (t < NT_ - 1){
        union { float f; unsigned u; } hv; hv.f = hn;
        unsigned* hq32 = (unsigned*)(Hq + (size_t)(t+1)*24576);
        __hip_atomic_store(&hq32[((j >> 1)*32 + bb)*2 + (j & 1)], hv.u,
                           __ATOMIC_RELAXED, __HIP_MEMORY_SCOPE_AGENT);
      }
    }
    __syncthreads();                       // per-wave vmcnt(0): h stores complete

    if (t < NT_ - 1){
      if (tid == 0)
        __hip_atomic_store(&flags[(size_t)blockIdx.x*4], (unsigned)(t + 1),
                           __ATOMIC_RELAXED, __HIP_MEMORY_SCOPE_AGENT);
      if (tid < GRU_NBLK){                 // parallel poll: one distinct flag/thread
        unsigned spins = 0u;
        while (__hip_atomic_load(&flags[(size_t)tid*4], __ATOMIC_RELAXED,
                                 __HIP_MEMORY_SCOPE_AGENT) < (unsigned)(t + 1) &&
               ++spins < 20000000u)
          __builtin_amdgcn_s_sleep(1);
      }
      __syncthreads();
    }
  }
}

// ---------------- attn_e[t][b][s] = enc[b][s][:] . h[t+1][b][:]  (fp32) ----------------
__global__ __launch_bounds__(256) void k_attn(const float* __restrict__ enc, const float* __restrict__ Hb1,
                                              float* __restrict__ ae){
  __shared__ float Es[64*36];
  __shared__ float Ht[24*36];
  const int b = blockIdx.x, s0 = blockIdx.y * 64;
  const int tid = threadIdx.x;
  const int s_l = tid & 63, tq = tid >> 6;
  const int r = tid >> 2, kq = tid & 3;
  float acc[6] = {0.f,0.f,0.f,0.f,0.f,0.f};
  for (int k0 = 0; k0 < 768; k0 += 32){
    __syncthreads();
    float4 e0 = *(const float4*)&enc[(size_t)(b*512 + s0 + r)*768 + k0 + kq*8];
    float4 e1 = *(const float4*)&enc[(size_t)(b*512 + s0 + r)*768 + k0 + kq*8 + 4];
    *(float4*)&Es[r*36 + kq*8]     = e0;
    *(float4*)&Es[r*36 + kq*8 + 4] = e1;
    if (tid < 192){
      int t = tid >> 3, k4 = tid & 7;
      *(float4*)&Ht[t*36 + k4*4] = *(const float4*)&Hb1[(size_t)t*24576 + b*768 + k0 + k4*4];
    }
    __syncthreads();
#pragma unroll
    for (int k4 = 0; k4 < 8; ++k4){
      float4 e = *(const float4*)&Es[s_l*36 + k4*4];
#pragma unroll
      for (int i = 0; i < 6; ++i){
        float4 h4 = *(const float4*)&Ht[(tq*6 + i)*36 + k4*4];
        acc[i] += e.x*h4.x + e.y*h4.y + e.z*h4.z + e.w*h4.w;
      }
    }
  }
#pragma unroll
  for (int i = 0; i < 6; ++i)
    ae[(size_t)((tq*6 + i)*32 + b)*512 + s0 + s_l] = acc[i];
}

// ---------------- masked softmax over S=512, in place ----------------
__global__ __launch_bounds__(256) void k_attnsoft(const int* __restrict__ x, float* __restrict__ ae){
  const int row = blockIdx.x;            // t*32+b
  const int b = row & 31;
  const int tid = threadIdx.x;
  __shared__ float red[256];
  float v0 = ae[(size_t)row*512 + tid];
  float v1 = ae[(size_t)row*512 + 256 + tid];
  if (x[b*512 + tid]        == 0) v0 = -1e9f;
  if (x[b*512 + 256 + tid]  == 0) v1 = -1e9f;
  float m = fmaxf(v0, v1);
  red[tid] = m; __syncthreads();
  for (int off = 128; off; off >>= 1){ if (tid < off) red[tid] = fmaxf(red[tid], red[tid+off]); __syncthreads(); }
  float M = red[0]; __syncthreads();
  float e0 = __expf(v0 - M), e1 = __expf(v1 - M);
  red[tid] = e0 + e1; __syncthreads();
  for (int off = 128; off; off >>= 1){ if (tid < off) red[tid] += red[tid+off]; __syncthreads(); }
  float inv = 1.f / red[0];
  ae[(size_t)row*512 + tid]       = e0 * inv;
  ae[(size_t)row*512 + 256 + tid] = e1 * inv;
}

// ---------------- ctx reduction folded directly into p_gen partials ----------------
__global__ __launch_bounds__(256) void k_ctx_pgen(const float* __restrict__ enc, const float* __restrict__ ah,
                                                  const float* __restrict__ wall, const float* __restrict__ Hb1,
                                                  const float* __restrict__ wg, float* __restrict__ pgacc){
  const int b = blockIdx.x;
  const int klane = threadIdx.x & 63;
  const int k = blockIdx.y * 64 + klane;
  const int tq = threadIdx.x >> 6;
  float acc[6] = {0.f,0.f,0.f,0.f,0.f,0.f};
  for (int s4 = 0; s4 < 512; s4 += 4){
    float e0 = enc[(size_t)(b*512 + s4 + 0)*768 + k];
    float e1 = enc[(size_t)(b*512 + s4 + 1)*768 + k];
    float e2 = enc[(size_t)(b*512 + s4 + 2)*768 + k];
    float e3 = enc[(size_t)(b*512 + s4 + 3)*768 + k];
#pragma unroll
    for (int i = 0; i < 6; ++i){
      float4 a4 = *(const float4*)&ah[(size_t)((tq*6 + i)*32 + b)*512 + s4];
      acc[i] = fmaf(a4.x, e0, acc[i]); acc[i] = fmaf(a4.y, e1, acc[i]);
      acc[i] = fmaf(a4.z, e2, acc[i]); acc[i] = fmaf(a4.w, e3, acc[i]);
    }
  }
  const float wgk = wg[k], wgh = wg[768 + k], wgc = wg[1536 + k];
#pragma unroll
  for (int i = 0; i < 6; ++i){
    const int t = tq*6 + i, row = t*32 + b;
    float p = acc[i]*wgc + wall[(size_t)row*768 + k]*wgk + Hb1[(size_t)t*24576 + b*768 + k]*wgh;
#pragma unroll
    for (int off = 32; off; off >>= 1) p += __shfl_down(p, off, 64);
    if (klane == 0) atomicAdd(&pgacc[row], p);
  }
}

// ---------------- vocab logits GEMM (bf16 MFMA), XCD-grouped grid ----------------
__global__ __launch_bounds__(256) void k_vgemm(const ushort_t* __restrict__ A2, const ushort_t* __restrict__ E2,
                                               float* __restrict__ out){
  __shared__ ushort_t ldsA[128*64];
  __shared__ ushort_t ldsB[128*64];
  const int wg = blockIdx.x;
  const int xcd = wg & 7, qq = wg >> 3;
  const int ntile = (qq / 6) * 8 + xcd;     // 0..239 (239 = all-OOB dummy)
  const int mtile = qq % 6;
  const int tid = threadIdx.x;
  const int w = tid >> 6, lane = tid & 63;
  const int lrow = lane >> 3, lpos = lane & 7;
  const int wm = w >> 1, wn = w & 1;
  const int q = lane >> 4, fr = lane & 15;
  f32x4 acc[4][4];
  f32x4 zero = {0.f, 0.f, 0.f, 0.f};
#pragma unroll
  for (int a = 0; a < 4; ++a)
#pragma unroll
    for (int c = 0; c < 4; ++c) acc[a][c] = zero;

  for (int k0 = 0; k0 < 768; k0 += 64){
    __syncthreads();
#pragma unroll
    for (int i = 0; i < 4; ++i){
      int row = w*32 + i*8 + lrow;          // 0..127
      int c   = lpos ^ (row & 7);           // XOR-swizzled source chunk
      const ushort_t* srcA = A2 + (size_t)(mtile*128 + row)*768 + k0 + c*8;
      int brow = ntile*128 + row; if (brow > V_ - 1) brow = V_ - 1;
      const ushort_t* srcB = E2 + (size_t)brow*768 + k0 + c*8;
      load_lds_16B(srcA, &ldsA[row*64 + lpos*8]);
      load_lds_16B(srcB, &ldsB[row*64 + lpos*8]);
    }
    __builtin_amdgcn_s_waitcnt(0);
    __syncthreads();
#pragma unroll
    for (int s = 0; s < 2; ++s){
      bf16x8 af[4], bfr[4];
#pragma unroll
      for (int mt = 0; mt < 4; ++mt){
        int row = wm*64 + mt*16 + fr;
        int ch = (s*4 + q) ^ (row & 7);
        af[mt] = *(const bf16x8*)&ldsA[row*64 + ch*8];
      }
#pragma unroll
      for (int nt = 0; nt < 4; ++nt){
        int row = wn*64 + nt*16 + fr;
        int ch = (s*4 + q) ^ (row & 7);
        bfr[nt] = *(const bf16x8*)&ldsB[row*64 + ch*8];
      }
#pragma unroll
      for (int mt = 0; mt < 4; ++mt)
#pragma unroll
        for (int nt = 0; nt < 4; ++nt)
          acc[mt][nt] = __builtin_amdgcn_mfma_f32_16x16x32_bf16(af[mt], bfr[nt], acc[mt][nt], 0, 0, 0);
    }
  }
#pragma unroll
  for (int mt = 0; mt < 4; ++mt){
#pragma unroll
    for (int nt = 0; nt < 4; ++nt){
      int gn = ntile*128 + wn*64 + nt*16 + fr;
      if (gn >= V_) continue;
#pragma unroll
      for (int rg = 0; rg < 4; ++rg){
        int gm = mtile*128 + wm*64 + mt*16 + q*4 + rg;   // A row = t*32+b
        int t = gm >> 5, b = gm & 31;
        out[(size_t)(b*24 + t)*V_ + gn] = acc[mt][nt][rg];
      }
    }
  }
}

// ---------------- vocab softmax (online) * p_gen, in place ----------------
__global__ __launch_bounds__(512) void k_vsoft(float* __restrict__ out, const float* __restrict__ pgacc,
                                               const float* __restrict__ wgb){
  const int row = blockIdx.x;            // b*24+t
  const int b = row / 24, t = row % 24;
  const float pg = 1.f / (1.f + __expf(-(pgacc[t*32 + b] + wgb[0])));
  const int tid = threadIdx.x;
  float* rp = out + (size_t)row * V_;
  const float4* rp4 = (const float4*)rp;
  float m = -3.0e38f, s = 0.f;
  for (int i = tid; i < 7630; i += 512){
    float4 v = rp4[i];
    float vm = fmaxf(fmaxf(v.x, v.y), fmaxf(v.z, v.w));
    float vs = __expf(v.x - vm) + __expf(v.y - vm) + __expf(v.z - vm) + __expf(v.w - vm);
    float nm = fmaxf(m, vm);
    s = s * __expf(m - nm) + vs * __expf(vm - nm);
    m = nm;
  }
  if (tid < 2){
    float v = rp[30520 + tid];
    float nm = fmaxf(m, v);
    s = s * __expf(m - nm) + __expf(v - nm);
    m = nm;
  }
#pragma unroll
  for (int off = 1; off < 64; off <<= 1){
    float m2 = __shfl_xor(m, off, 64), s2 = __shfl_xor(s, off, 64);
    float nm = fmaxf(m, m2);
    s = s*__expf(m - nm) + s2*__expf(m2 - nm);
    m = nm;
  }
  __shared__ float rm[8], rs[8];
  const int wid = tid >> 6;
  if ((tid & 63) == 0){ rm[wid] = m; rs[wid] = s; }
  __syncthreads();
  if (tid == 0){
    float M = rm[0], S = rs[0];
#pragma unroll
    for (int i = 1; i < 8; ++i){
      float m2 = rm[i], s2 = rs[i];
      float nm = fmaxf(M, m2);
      S = S*__expf(M - nm) + s2*__expf(m2 - nm);
      M = nm;
    }
    rm[0] = M; rs[0] = pg / S;
  }
  __syncthreads();
  const float M = rm[0], inv = rs[0];
  for (int i = tid; i < 7630; i += 512){
    float4 v = rp4[i];
    v.x = __expf(v.x - M) * inv;
    v.y = __expf(v.y - M) * inv;
    v.z = __expf(v.z - M) * inv;
    v.w = __expf(v.w - M) * inv;
    ((float4*)rp)[i] = v;
  }
  if (tid < 2) rp[30520 + tid] = __expf(rp[30520 + tid] - M) * inv;
}

// ---------------- scatter copy-distribution (separate kernel: boundary coherence) ----------------
__global__ void k_scatter(const float* __restrict__ ah, const float* __restrict__ pgacc,
                          const float* __restrict__ wgb, const int* __restrict__ x,
                          float* __restrict__ out){
  int idx = blockIdx.x * 256 + threadIdx.x;       // over 24*32*512
  int s = idx & 511;
  int row = idx >> 9;                              // t*32+b
  int t = row >> 5, b = row & 31;
  float pg = 1.f / (1.f + __expf(-(pgacc[row] + wgb[0])));
  float val = ah[idx] * (1.f - pg);
  int col = x[b*512 + s];
  atomicAdd(&out[(size_t)(b*24 + t)*V_ + col], val);
}

extern "C" void kernel_launch(void* const* d_in, const int* in_sizes, int n_in,
                              void* d_out, int out_size, void* d_ws, size_t ws_size,
                              hipStream_t stream){
  (void)in_sizes; (void)n_in; (void)out_size; (void)ws_size;
  const int*   x      = (const int*)  d_in[0];
  const float* dec    = (const float*)d_in[1];
  const float* enc    = (const float*)d_in[2];
  const float* hidden = (const float*)d_in[3];
  const int*   teach  = (const int*)  d_in[4];
  const float* embed  = (const float*)d_in[5];
  const float* wih    = (const float*)d_in[6];
  const float* whh    = (const float*)d_in[7];
  const float* bih    = (const float*)d_in[8];
  const float* bhh    = (const float*)d_in[9];
  const float* wg     = (const float*)d_in[10];
  const float* wgb    = (const float*)d_in[11];
  float* out = (float*)d_out;

  char* p = (char*)d_ws;
  auto alloc = [&](size_t bytes){ void* r = (void*)p; p += (bytes + 255) & ~(size_t)255; return r; };
  ushort_t* E2  = (ushort_t*)alloc((size_t)V_ * H_ * 2);            // 46.9 MB
  ushort_t* A2  = (ushort_t*)alloc((size_t)768 * 768 * 2);          // 1.2 MB
  float* wall   = (float*)alloc((size_t)NT_ * B_ * H_ * 4);         // 2.4 MB (b-major, ctx_pgen)
  float* wallT  = (float*)alloc((size_t)NT_ * B_ * H_ * 4);         // 2.4 MB (pair-major, GRU)
  float* Hb     = (float*)alloc((size_t)(NT_+1) * B_ * H_ * 4);     // 2.5 MB
  float* Hq     = (float*)alloc((size_t)(NT_+1) * B_ * H_ * 4);     // 2.5 MB (pair layout)
  float* ae     = (float*)alloc((size_t)NT_ * B_ * S_ * 4);         // 1.6 MB
  float* pgacc  = (float*)alloc(768 * 4);
  unsigned* flags = (unsigned*)alloc(768 * 4);                      // 192 flags, 16B stride

  const int prep_items  = NC4 + NWALL + NINIT + 768 + 768;
  const int prep_blocks = (prep_items + 255) / 256;

  // 8 dispatches (gi_gemm fused into gru)
  k_prep<<<prep_blocks, 256, 0, stream>>>(embed, dec, teach, hidden, E2, wall, wallT, Hq, Hb, pgacc, flags);
  k_gru_all<<<GRU_NBLK, GRU_TPB, 0, stream>>>(wallT, wih, whh, bih, bhh, hidden, Hq, Hb, A2, flags);
  k_attn<<<dim3(32, 8), 256, 0, stream>>>(enc, Hb + 24576, ae);
  k_attnsoft<<<768, 256, 0, stream>>>(x, ae);
  k_ctx_pgen<<<dim3(32, 12), 256, 0, stream>>>(enc, ae, wall, Hb + 24576, wg, pgacc);
  k_vgemm<<<1440, 256, 0, stream>>>(A2, E2, out);
  k_vsoft<<<768, 512, 0, stream>>>(out, pgacc, wgb);
  k_scatter<<<(NT_*B_*S_)/256, 256, 0, stream>>>(ae, pgacc, wgb, x, out);
}

// Round 7
// 670.809 us; speedup vs baseline: 1.9733x; 1.0530x over previous
//
#include <hip/hip_runtime.h>
#include <cstdint>

#define B_  32
#define S_  512
#define H_  768
#define V_  30522
#define NT_ 24          // N_UPDATE * MAX_LEN sequential steps
#define H3  2304
#define NC4   (V_*H_/4)           // 5860224 float4 casts for E2
#define NWALL (NT_*B_*H_)         // 589824
#define NINIT (B_*H_)             // 24576

#define GRU_NBLK 192
#define GRU_TPB  512
#define GRU_JPB  4                // j columns per block
#define GRU_RPB  12               // rows per block = 3 gates * GRU_JPB
#define NTILE_   240              // vgemm n tiles (incl. dummy 239)

typedef unsigned short ushort_t;
typedef __attribute__((ext_vector_type(8))) short bf16x8;
typedef __attribute__((ext_vector_type(4))) float f32x4;

__device__ __forceinline__ ushort_t f2bf(float f){
  union { float f; unsigned u; } v; v.f = f;
  unsigned r = v.u + 0x7fffu + ((v.u >> 16) & 1u);
  return (ushort_t)(r >> 16);
}

// ---------------- async global->LDS 16B helper ----------------
__device__ __forceinline__ void load_lds_16B(const void* g, void* l){
  auto gp = reinterpret_cast<const __attribute__((address_space(1))) unsigned int*>(
      reinterpret_cast<uintptr_t>(g));
  auto lp = reinterpret_cast<__attribute__((address_space(3))) unsigned int*>(
      reinterpret_cast<uintptr_t>(l));
  __builtin_amdgcn_global_load_lds(gp, lp, 16, 0, 0);
}

// ---------------- fused prep: E2 cast + W_all build (2 layouts) + h0 init + zeroing ----------------
__global__ void k_prep(const float* __restrict__ embed, const float* __restrict__ dec,
                       const int* __restrict__ teacher, const float* __restrict__ hidden,
                       ushort_t* __restrict__ E2, float* __restrict__ wall,
                       float* __restrict__ wallT, float* __restrict__ Hq, float* __restrict__ Hb,
                       float* __restrict__ pgacc, unsigned* __restrict__ flags){
  int idx = blockIdx.x * 256 + threadIdx.x;
  if (idx < NC4){                                  // E2 = bf16(embed)
    float4 v = ((const float4*)embed)[idx];
    uint2 o;
    o.x = (unsigned)f2bf(v.x) | ((unsigned)f2bf(v.y) << 16);
    o.y = (unsigned)f2bf(v.z) | ((unsigned)f2bf(v.w) << 16);
    ((uint2*)E2)[idx] = o;
    return;
  }
  idx -= NC4;
  if (idx < NWALL){                                // W_all[t][b][k] (both layouts)
    int k  = idx % H_;
    int rb = idx / H_;
    int t = rb >> 5, b = rb & 31;
    int jj = t >> 3, kk = t & 7;
    float v;
    if (kk == 0) v = dec[(b*3 + jj)*H_ + k];
    else { int tok = teacher[(b*3 + jj)*8 + kk - 1]; v = embed[(size_t)tok*H_ + k]; }
    wall[idx] = v;                                              // [t*32+b][k] (ctx_pgen)
    wallT[(size_t)t*24576 + ((k >> 1)*B_ + b)*2 + (k & 1)] = v; // pair-major (GRU)
    return;
  }
  idx -= NWALL;
  if (idx < NINIT){                                // h0 -> Hb, Hq layouts
    int b = idx / H_, k = idx % H_;
    float v = hidden[idx];
    Hb[idx] = v;
    Hq[((k >> 1)*B_ + b)*2 + (k & 1)] = v;
    return;
  }
  idx -= NINIT;
  if (idx < 768){ pgacc[idx] = 0.f; return; }      // zero p_gen accumulator
  idx -= 768;
  if (idx < 768) flags[idx] = 0u;                  // zero arrival flags (192 x 16B)
}

// ---------------- persistent GRU v7: hoisted loads, float4 LDS reads ----------------
// Same structure as round-6 (dual gh/gi dots, flag barrier, direct h publish),
// but: (a) the 24 h-atomic and 24 wallT loads are hoisted into registers in
// 2 chunks of 12 (deep memory-level parallelism, no interleaved stalls);
// (b) LDS weight reads are float4 = 2 K-steps/read (ds_read count halved).
// Accumulation order per row preserved (i ascending).
__global__ __launch_bounds__(GRU_TPB) void k_gru_all(const float* __restrict__ wallT, const float* __restrict__ wih,
                                                     const float* __restrict__ whh, const float* __restrict__ bih,
                                                     const float* __restrict__ bhh, const float* __restrict__ hidden,
                                                     float* __restrict__ Hq, float* __restrict__ Hb,
                                                     ushort_t* __restrict__ A2, unsigned* __restrict__ flags){
  __shared__ float wsh[GRU_RPB*768];       // 36864 B: whh rows [r][k], r = gate*4+jl
  __shared__ float wsi[GRU_RPB*768];       // 36864 B: wih rows
  __shared__ float red[16*776];            // 49664 B: [ks][row*32+b], rows 0..11 hh / 12..23 ih
  __shared__ float bsh[GRU_RPB], bsi[GRU_RPB];
  const int tid = threadIdx.x;
  const int j0 = blockIdx.x * GRU_JPB;

  for (int idx4 = tid; idx4 < GRU_RPB*192; idx4 += GRU_TPB){
    int r = idx4 / 192, k4 = idx4 % 192;
    int gate = r >> 2, jl = r & 3;
    *(float4*)&wsh[r*768 + k4*4] = *(const float4*)&whh[(size_t)(gate*768 + j0 + jl)*768 + k4*4];
    *(float4*)&wsi[r*768 + k4*4] = *(const float4*)&wih[(size_t)(gate*768 + j0 + jl)*768 + k4*4];
  }
  if (tid < GRU_RPB){
    bsh[tid] = bhh[(tid >> 2)*768 + j0 + (tid & 3)];
    bsi[tid] = bih[(tid >> 2)*768 + j0 + (tid & 3)];
  }
  __syncthreads();

  const int ks = tid >> 5, b = tid & 31;   // compute mapping: 16 kslices x 32 batch
  const int jl = tid >> 5, bb = tid & 31;  // finalize mapping (tid < 128)
  const int j  = j0 + (jl & 3);
  float hp = 0.f;
  if (tid < 128) hp = hidden[bb*768 + j];  // h0 ([1,B,H] b-major), registered

  for (int t = 0; t < NT_; ++t){
    const unsigned long long* hsrc = (const unsigned long long*)(Hq + (size_t)t*24576);
    const float2* wsrc = (const float2*)(wallT + (size_t)t*24576);

    float acch[GRU_RPB], acci[GRU_RPB];
#pragma unroll
    for (int r = 0; r < GRU_RPB; ++r){ acch[r] = 0.f; acci[r] = 0.f; }

#pragma unroll
    for (int c = 0; c < 2; ++c){
      // hoist 12 h-atomic + 12 wallT loads (independent, pipelined)
      unsigned long long hreg[12];
      float2 wreg[12];
#pragma unroll
      for (int i = 0; i < 12; ++i)
        hreg[i] = __hip_atomic_load(&hsrc[(size_t)(ks*24 + c*12 + i)*32 + b],
                                    __ATOMIC_RELAXED, __HIP_MEMORY_SCOPE_AGENT);
#pragma unroll
      for (int i = 0; i < 12; ++i)
        wreg[i] = wsrc[(size_t)(ks*24 + c*12 + i)*32 + b];

#pragma unroll
      for (int p = 0; p < 6; ++p){         // pairs of i -> float4 LDS weight reads
        union { unsigned long long u; float f[2]; } ca, cb;
        ca.u = hreg[2*p]; cb.u = hreg[2*p + 1];
        const float h0a = ca.f[0], h1a = ca.f[1], h0b = cb.f[0], h1b = cb.f[1];
        const float2 wa = wreg[2*p], wb = wreg[2*p + 1];
        const int wo = ks*48 + c*24 + p*4;
#pragma unroll
        for (int r = 0; r < GRU_RPB; ++r){
          const float4 wh = *(const float4*)&wsh[r*768 + wo];
          const float4 wi = *(const float4*)&wsi[r*768 + wo];
          acch[r] += h0a*wh.x + h1a*wh.y + h0b*wh.z + h1b*wh.w;
          acci[r] += wa.x*wi.x + wa.y*wi.y + wb.x*wi.z + wb.y*wi.w;
        }
      }
    }
#pragma unroll
    for (int r = 0; r < GRU_RPB; ++r){
      red[ks*776 + r*32 + b]             = acch[r];
      red[ks*776 + (GRU_RPB + r)*32 + b] = acci[r];
    }
    __syncthreads();

    if (tid < 128){
      float aR = 0.f, aZ = 0.f, aN = 0.f, iR = 0.f, iZ = 0.f, iN = 0.f;
#pragma unroll
      for (int k8 = 0; k8 < 16; ++k8){
        const float* rb_ = &red[k8*776 + jl*32 + bb];
        aR += rb_[0*128]; aZ += rb_[1*128]; aN += rb_[2*128];
        iR += rb_[3*128]; iZ += rb_[4*128]; iN += rb_[5*128];
      }
      aR += bsh[jl]; aZ += bsh[4 + jl]; aN += bsh[8 + jl];
      const float ir = iR + bsi[jl], iz = iZ + bsi[4 + jl], inn = iN + bsi[8 + jl];
      float rg = 1.f / (1.f + __expf(-(ir + aR)));
      float zg = 1.f / (1.f + __expf(-(iz + aZ)));
      float e2 = __expf(-2.f*(inn + rg * aN));
      float ng = (1.f - e2) / (1.f + e2);
      float hn = (1.f - zg)*ng + zg*hp;
      hp = hn;
      Hb[(size_t)(t+1)*24576 + bb*768 + j] = hn;
      A2[(size_t)(t*32 + bb)*768 + j] = f2bf(hn);
      if (t < NT_ - 1){
        union { float f; unsigned u; } hv; hv.f = hn;
        unsigned* hq32 = (unsigned*)(Hq + (size_t)(t+1)*24576);
        __hip_atomic_store(&hq32[((j >> 1)*32 + bb)*2 + (j & 1)], hv.u,
                           __ATOMIC_RELAXED, __HIP_MEMORY_SCOPE_AGENT);
      }
    }
    __syncthreads();                       // per-wave vmcnt(0): h stores complete

    if (t < NT_ - 1){
      if (tid == 0)
        __hip_atomic_store(&flags[(size_t)blockIdx.x*4], (unsigned)(t + 1),
                           __ATOMIC_RELAXED, __HIP_MEMORY_SCOPE_AGENT);
      if (tid < GRU_NBLK){                 // parallel poll: one distinct flag/thread
        unsigned spins = 0u;
        while (__hip_atomic_load(&flags[(size_t)tid*4], __ATOMIC_RELAXED,
                                 __HIP_MEMORY_SCOPE_AGENT) < (unsigned)(t + 1) &&
               ++spins < 20000000u)
          __builtin_amdgcn_s_sleep(1);
      }
      __syncthreads();
    }
  }
}

// ---------------- attn_e[t][b][s] = enc[b][s][:] . h[t+1][b][:]  (fp32) ----------------
__global__ __launch_bounds__(256) void k_attn(const float* __restrict__ enc, const float* __restrict__ Hb1,
                                              float* __restrict__ ae){
  __shared__ float Es[64*36];
  __shared__ float Ht[24*36];
  const int b = blockIdx.x, s0 = blockIdx.y * 64;
  const int tid = threadIdx.x;
  const int s_l = tid & 63, tq = tid >> 6;
  const int r = tid >> 2, kq = tid & 3;
  float acc[6] = {0.f,0.f,0.f,0.f,0.f,0.f};
  for (int k0 = 0; k0 < 768; k0 += 32){
    __syncthreads();
    float4 e0 = *(const float4*)&enc[(size_t)(b*512 + s0 + r)*768 + k0 + kq*8];
    float4 e1 = *(const float4*)&enc[(size_t)(b*512 + s0 + r)*768 + k0 + kq*8 + 4];
    *(float4*)&Es[r*36 + kq*8]     = e0;
    *(float4*)&Es[r*36 + kq*8 + 4] = e1;
    if (tid < 192){
      int t = tid >> 3, k4 = tid & 7;
      *(float4*)&Ht[t*36 + k4*4] = *(const float4*)&Hb1[(size_t)t*24576 + b*768 + k0 + k4*4];
    }
    __syncthreads();
#pragma unroll
    for (int k4 = 0; k4 < 8; ++k4){
      float4 e = *(const float4*)&Es[s_l*36 + k4*4];
#pragma unroll
      for (int i = 0; i < 6; ++i){
        float4 h4 = *(const float4*)&Ht[(tq*6 + i)*36 + k4*4];
        acc[i] += e.x*h4.x + e.y*h4.y + e.z*h4.z + e.w*h4.w;
      }
    }
  }
#pragma unroll
  for (int i = 0; i < 6; ++i)
    ae[(size_t)((tq*6 + i)*32 + b)*512 + s0 + s_l] = acc[i];
}

// ---------------- masked softmax over S=512, in place ----------------
__global__ __launch_bounds__(256) void k_attnsoft(const int* __restrict__ x, float* __restrict__ ae){
  const int row = blockIdx.x;            // t*32+b
  const int b = row & 31;
  const int tid = threadIdx.x;
  __shared__ float red[256];
  float v0 = ae[(size_t)row*512 + tid];
  float v1 = ae[(size_t)row*512 + 256 + tid];
  if (x[b*512 + tid]        == 0) v0 = -1e9f;
  if (x[b*512 + 256 + tid]  == 0) v1 = -1e9f;
  float m = fmaxf(v0, v1);
  red[tid] = m; __syncthreads();
  for (int off = 128; off; off >>= 1){ if (tid < off) red[tid] = fmaxf(red[tid], red[tid+off]); __syncthreads(); }
  float M = red[0]; __syncthreads();
  float e0 = __expf(v0 - M), e1 = __expf(v1 - M);
  red[tid] = e0 + e1; __syncthreads();
  for (int off = 128; off; off >>= 1){ if (tid < off) red[tid] += red[tid+off]; __syncthreads(); }
  float inv = 1.f / red[0];
  ae[(size_t)row*512 + tid]       = e0 * inv;
  ae[(size_t)row*512 + 256 + tid] = e1 * inv;
}

// ---------------- ctx reduction folded directly into p_gen partials ----------------
__global__ __launch_bounds__(256) void k_ctx_pgen(const float* __restrict__ enc, const float* __restrict__ ah,
                                                  const float* __restrict__ wall, const float* __restrict__ Hb1,
                                                  const float* __restrict__ wg, float* __restrict__ pgacc){
  const int b = blockIdx.x;
  const int klane = threadIdx.x & 63;
  const int k = blockIdx.y * 64 + klane;
  const int tq = threadIdx.x >> 6;
  float acc[6] = {0.f,0.f,0.f,0.f,0.f,0.f};
  for (int s4 = 0; s4 < 512; s4 += 4){
    float e0 = enc[(size_t)(b*512 + s4 + 0)*768 + k];
    float e1 = enc[(size_t)(b*512 + s4 + 1)*768 + k];
    float e2 = enc[(size_t)(b*512 + s4 + 2)*768 + k];
    float e3 = enc[(size_t)(b*512 + s4 + 3)*768 + k];
#pragma unroll
    for (int i = 0; i < 6; ++i){
      float4 a4 = *(const float4*)&ah[(size_t)((tq*6 + i)*32 + b)*512 + s4];
      acc[i] = fmaf(a4.x, e0, acc[i]); acc[i] = fmaf(a4.y, e1, acc[i]);
      acc[i] = fmaf(a4.z, e2, acc[i]); acc[i] = fmaf(a4.w, e3, acc[i]);
    }
  }
  const float wgk = wg[k], wgh = wg[768 + k], wgc = wg[1536 + k];
#pragma unroll
  for (int i = 0; i < 6; ++i){
    const int t = tq*6 + i, row = t*32 + b;
    float p = acc[i]*wgc + wall[(size_t)row*768 + k]*wgk + Hb1[(size_t)t*24576 + b*768 + k]*wgh;
#pragma unroll
    for (int off = 32; off; off >>= 1) p += __shfl_down(p, off, 64);
    if (klane == 0) atomicAdd(&pgacc[row], p);
  }
}

// ---------------- vocab logits GEMM (bf16 MFMA) + per-tile softmax stats ----------------
// XCD-grouped 1D grid 1440. Epilogue additionally emits per-(row, ntile)
// online-softmax stats (max, sumexp over this block's <=128 valid cols) into
// vstat so k_vsoft can skip its full 94 MB pass-1 scan.
__global__ __launch_bounds__(256) void k_vgemm(const ushort_t* __restrict__ A2, const ushort_t* __restrict__ E2,
                                               float* __restrict__ out, float2* __restrict__ vstat){
  __shared__ ushort_t ldsA[128*64];
  __shared__ ushort_t ldsB[128*64];
  __shared__ float smx[128*2], sms[128*2];
  const int wg = blockIdx.x;
  const int xcd = wg & 7, qq = wg >> 3;
  const int ntile = (qq / 6) * 8 + xcd;     // 0..239 (239 = all-OOB dummy)
  const int mtile = qq % 6;
  const int tid = threadIdx.x;
  const int w = tid >> 6, lane = tid & 63;
  const int lrow = lane >> 3, lpos = lane & 7;
  const int wm = w >> 1, wn = w & 1;
  const int q = lane >> 4, fr = lane & 15;
  f32x4 acc[4][4];
  f32x4 zero = {0.f, 0.f, 0.f, 0.f};
#pragma unroll
  for (int a = 0; a < 4; ++a)
#pragma unroll
    for (int c = 0; c < 4; ++c) acc[a][c] = zero;

  for (int k0 = 0; k0 < 768; k0 += 64){
    __syncthreads();
#pragma unroll
    for (int i = 0; i < 4; ++i){
      int row = w*32 + i*8 + lrow;          // 0..127
      int c   = lpos ^ (row & 7);           // XOR-swizzled source chunk
      const ushort_t* srcA = A2 + (size_t)(mtile*128 + row)*768 + k0 + c*8;
      int brow = ntile*128 + row; if (brow > V_ - 1) brow = V_ - 1;
      const ushort_t* srcB = E2 + (size_t)brow*768 + k0 + c*8;
      load_lds_16B(srcA, &ldsA[row*64 + lpos*8]);
      load_lds_16B(srcB, &ldsB[row*64 + lpos*8]);
    }
    __builtin_amdgcn_s_waitcnt(0);
    __syncthreads();
#pragma unroll
    for (int s = 0; s < 2; ++s){
      bf16x8 af[4], bfr[4];
#pragma unroll
      for (int mt = 0; mt < 4; ++mt){
        int row = wm*64 + mt*16 + fr;
        int ch = (s*4 + q) ^ (row & 7);
        af[mt] = *(const bf16x8*)&ldsA[row*64 + ch*8];
      }
#pragma unroll
      for (int nt = 0; nt < 4; ++nt){
        int row = wn*64 + nt*16 + fr;
        int ch = (s*4 + q) ^ (row & 7);
        bfr[nt] = *(const bf16x8*)&ldsB[row*64 + ch*8];
      }
#pragma unroll
      for (int mt = 0; mt < 4; ++mt)
#pragma unroll
        for (int nt = 0; nt < 4; ++nt)
          acc[mt][nt] = __builtin_amdgcn_mfma_f32_16x16x32_bf16(af[mt], bfr[nt], acc[mt][nt], 0, 0, 0);
    }
  }
  // ---- store C + per-row stats over this block's 128 cols ----
#pragma unroll
  for (int mt = 0; mt < 4; ++mt){
#pragma unroll
    for (int rg = 0; rg < 4; ++rg){
      float m = -3.0e38f, ssum = 0.f;
#pragma unroll
      for (int nt = 0; nt < 4; ++nt){
        int gn = ntile*128 + wn*64 + nt*16 + fr;
        if (gn < V_){
          float v = acc[mt][nt][rg];
          int gm = mtile*128 + wm*64 + mt*16 + q*4 + rg;   // A row = t*32+b
          int t = gm >> 5, b = gm & 31;
          out[(size_t)(b*24 + t)*V_ + gn] = v;
          float nm = fmaxf(m, v);
          ssum = ssum*__expf(m - nm) + __expf(v - nm);
          m = nm;
        }
      }
      // reduce over the 16 fr lanes (stays within each 16-lane q-group)
#pragma unroll
      for (int off = 1; off < 16; off <<= 1){
        float m2 = __shfl_xor(m, off, 64), s2 = __shfl_xor(ssum, off, 64);
        float nm = fmaxf(m, m2);
        ssum = ssum*__expf(m - nm) + s2*__expf(m2 - nm);
        m = nm;
      }
      if (fr == 0){
        int rl = wm*64 + mt*16 + q*4 + rg;   // row_local 0..127
        smx[rl*2 + wn] = m; sms[rl*2 + wn] = ssum;
      }
    }
  }
  __syncthreads();
  if (tid < 128){
    float m0 = smx[tid*2], s0 = sms[tid*2], m1 = smx[tid*2 + 1], s1 = sms[tid*2 + 1];
    float nm = fmaxf(m0, m1);
    float ss = s0*__expf(m0 - nm) + s1*__expf(m1 - nm);
    int gm = mtile*128 + tid;
    int t = gm >> 5, b2 = gm & 31;
    vstat[(size_t)(b2*24 + t)*NTILE_ + ntile] = make_float2(nm, ss);
  }
}

// ---------------- vocab softmax * p_gen + fused scatter, in place ----------------
// Pass 1 reads 240 float2 stats/row (not 94 MB of logits). After the
// normalize pass, this block owns its whole row: the 512 scatter adds use
// WORKGROUP-scope atomics -> buffer_atomic without sc1 -> RMW in this XCD's
// own L2, where the block's write-through dense stores already are (after
// __syncthreads vmcnt drain). No cache-wide fence needed.
__global__ __launch_bounds__(512) void k_vsoft_sc(float* __restrict__ out, const float* __restrict__ pgacc,
                                                  const float* __restrict__ wgb, const float2* __restrict__ vstat,
                                                  const float* __restrict__ ah, const int* __restrict__ x){
  const int row = blockIdx.x;            // b*24+t
  const int b = row / 24, t = row % 24;
  const float pg = 1.f / (1.f + __expf(-(pgacc[t*32 + b] + wgb[0])));
  const int tid = threadIdx.x;
  float* rp = out + (size_t)row * V_;
  float m = -3.0e38f, s = 0.f;
  if (tid < NTILE_){
    float2 st = vstat[(size_t)row*NTILE_ + tid];
    m = st.x; s = st.y;
  }
#pragma unroll
  for (int off = 1; off < 64; off <<= 1){
    float m2 = __shfl_xor(m, off, 64), s2 = __shfl_xor(s, off, 64);
    float nm = fmaxf(m, m2);
    s = s*__expf(m - nm) + s2*__expf(m2 - nm);
    m = nm;
  }
  __shared__ float rm[8], rs[8];
  const int wid = tid >> 6;
  if ((tid & 63) == 0){ rm[wid] = m; rs[wid] = s; }
  __syncthreads();
  if (tid == 0){
    float M = rm[0], S = rs[0];
#pragma unroll
    for (int i = 1; i < 8; ++i){
      float m2 = rm[i], s2 = rs[i];
      float nm = fmaxf(M, m2);
      S = S*__expf(M - nm) + s2*__expf(m2 - nm);
      M = nm;
    }
    rm[0] = M; rs[0] = pg / S;
  }
  __syncthreads();
  const float M = rm[0], inv = rs[0];
  const float4* rp4 = (const float4*)rp;
  for (int i = tid; i < 7630; i += 512){
    float4 v = rp4[i];
    v.x = __expf(v.x - M) * inv;
    v.y = __expf(v.y - M) * inv;
    v.z = __expf(v.z - M) * inv;
    v.w = __expf(v.w - M) * inv;
    ((float4*)rp)[i] = v;
  }
  if (tid < 2) rp[30520 + tid] = __expf(rp[30520 + tid] - M) * inv;
  // ---- fused scatter (normalized ah; this block owns the row) ----
  __syncthreads();                       // all waves' dense stores drained into L2
  {
    float val = ah[(size_t)(t*32 + b)*512 + tid] * (1.f - pg);
    int col = x[b*512 + tid];
    __hip_atomic_fetch_add(&rp[col], val, __ATOMIC_RELAXED, __HIP_MEMORY_SCOPE_WORKGROUP);
  }
}

extern "C" void kernel_launch(void* const* d_in, const int* in_sizes, int n_in,
                              void* d_out, int out_size, void* d_ws, size_t ws_size,
                              hipStream_t stream){
  (void)in_sizes; (void)n_in; (void)out_size; (void)ws_size;
  const int*   x      = (const int*)  d_in[0];
  const float* dec    = (const float*)d_in[1];
  const float* enc    = (const float*)d_in[2];
  const float* hidden = (const float*)d_in[3];
  const int*   teach  = (const int*)  d_in[4];
  const float* embed  = (const float*)d_in[5];
  const float* wih    = (const float*)d_in[6];
  const float* whh    = (const float*)d_in[7];
  const float* bih    = (const float*)d_in[8];
  const float* bhh    = (const float*)d_in[9];
  const float* wg     = (const float*)d_in[10];
  const float* wgb    = (const float*)d_in[11];
  float* out = (float*)d_out;

  char* p = (char*)d_ws;
  auto alloc = [&](size_t bytes){ void* r = (void*)p; p += (bytes + 255) & ~(size_t)255; return r; };
  ushort_t* E2  = (ushort_t*)alloc((size_t)V_ * H_ * 2);            // 46.9 MB
  ushort_t* A2  = (ushort_t*)alloc((size_t)768 * 768 * 2);          // 1.2 MB
  float* wall   = (float*)alloc((size_t)NT_ * B_ * H_ * 4);         // 2.4 MB (b-major, ctx_pgen)
  float* wallT  = (float*)alloc((size_t)NT_ * B_ * H_ * 4);         // 2.4 MB (pair-major, GRU)
  float* Hb     = (float*)alloc((size_t)(NT_+1) * B_ * H_ * 4);     // 2.5 MB
  float* Hq     = (float*)alloc((size_t)(NT_+1) * B_ * H_ * 4);     // 2.5 MB (pair layout)
  float* ae     = (float*)alloc((size_t)NT_ * B_ * S_ * 4);         // 1.6 MB
  float2* vstat = (float2*)alloc((size_t)768 * NTILE_ * 8);         // 1.5 MB
  float* pgacc  = (float*)alloc(768 * 4);
  unsigned* flags = (unsigned*)alloc(768 * 4);                      // 192 flags, 16B stride

  const int prep_items  = NC4 + NWALL + NINIT + 768 + 768;
  const int prep_blocks = (prep_items + 255) / 256;

  // 7 dispatches (scatter fused into vsoft)
  k_prep<<<prep_blocks, 256, 0, stream>>>(embed, dec, teach, hidden, E2, wall, wallT, Hq, Hb, pgacc, flags);
  k_gru_all<<<GRU_NBLK, GRU_TPB, 0, stream>>>(wallT, wih, whh, bih, bhh, hidden, Hq, Hb, A2, flags);
  k_attn<<<dim3(32, 8), 256, 0, stream>>>(enc, Hb + 24576, ae);
  k_attnsoft<<<768, 256, 0, stream>>>(x, ae);
  k_ctx_pgen<<<dim3(32, 12), 256, 0, stream>>>(enc, ae, wall, Hb + 24576, wg, pgacc);
  k_vgemm<<<1440, 256, 0, stream>>>(A2, E2, out, vstat);
  k_vsoft_sc<<<768, 512, 0, stream>>>(out, pgacc, wgb, vstat, ae, x);
}